// Round 4
// baseline (1650.658 us; speedup 1.0000x reference)
//
#include <hip/hip_runtime.h>
#include <hip/hip_bf16.h>
#include <cstdint>
#include <cstddef>

using bf16 = __hip_bfloat16;

typedef __attribute__((ext_vector_type(4))) float f32x4;
typedef __attribute__((ext_vector_type(8))) short s16x8;

__device__ __forceinline__ bf16 to_bf16(float v) { return __float2bfloat16(v); }

struct alignas(8) bf16x4_pack { bf16 x, y, z, w; };

// bijective XCD-chunking swizzle (m204)
__device__ __forceinline__ int xcd_swz(int orig, int nwg) {
    int xcd = orig & 7, base = orig >> 3;
    int q = nwg >> 3, r = nwg & 7;
    return (xcd < r ? xcd * (q + 1) : r * (q + 1) + (xcd - r) * q) + base;
}

#define BAR()        asm volatile("s_barrier" ::: "memory")
#define WAITV8_BAR() asm volatile("s_waitcnt vmcnt(8)\ns_barrier" ::: "memory")
#define WAITV4_BAR() asm volatile("s_waitcnt vmcnt(4)\ns_barrier" ::: "memory")
#define WAITV0_BAR() asm volatile("s_waitcnt vmcnt(0)\ns_barrier" ::: "memory")

// ---------------- fp32 -> bf16 elementwise ----------------
__global__ void k_conv_f32_bf16(const float* __restrict__ in, bf16* __restrict__ out, int n4) {
    int i = blockIdx.x * blockDim.x + threadIdx.x;
    if (i >= n4) return;
    float4 v = ((const float4*)in)[i];
    bf16x4_pack o{to_bf16(v.x), to_bf16(v.y), to_bf16(v.z), to_bf16(v.w)};
    ((bf16x4_pack*)out)[i] = o;
}

// ---------------- fp32 [K][N] -> bf16 [N][K] tiled transpose ----------------
__global__ __launch_bounds__(256) void k_transpose_f32_bf16(
    const float* __restrict__ in, bf16* __restrict__ out,
    int K, int N, long inz, long outz)
{
    __shared__ float t[32][33];
    in  += (long)blockIdx.z * inz;
    out += (long)blockIdx.z * outz;
    int n0 = blockIdx.x * 32, k0 = blockIdx.y * 32;
    int tx = threadIdx.x & 31, ty = threadIdx.x >> 5;
#pragma unroll
    for (int r = 0; r < 32; r += 8)
        t[ty + r][tx] = in[(long)(k0 + ty + r) * N + (n0 + tx)];
    __syncthreads();
#pragma unroll
    for (int r = 0; r < 32; r += 8)
        out[(long)(n0 + ty + r) * K + (k0 + tx)] = to_bf16(t[tx][ty + r]);
}

// ---------------- async global->LDS 16B helper ----------------
__device__ __forceinline__ void gload_lds16(const void* g, void* l) {
    __builtin_amdgcn_global_load_lds(
        (const __attribute__((address_space(1))) void*)g,
        (__attribute__((address_space(3))) void*)l,
        16, 0, 0);
}

// ================= 256x256 BK=64 8-wave deep-pipelined GEMM (T2+T3+T4+T5) =================
// C = act(A[M,K] * W^T[N,K] + bias). 512 thr = 8 waves (2M x 4N), per-wave C 128x64.
// Deep schedule: at phase 0 of tile t, issue ALL 8 loads of tile t+1 (kh0 A,B then kh1 A,B).
// Waits: end-ph1 vmcnt(8)  -> t's kh1 landed (issued 6 phases earlier);
//        end-ph3 vmcnt(4)  -> t+1's kh0 landed (issued 4 phases earlier); kh1 stays in flight.
// Swizzle: 16B-block k16' = k16 ^ (row&3) on stage-source AND ds_read (both-sides, rule #21).
template<int ACT, int OUTF, int OUTB>   // ACT: 0 none, 1 relu, 2 silu
__global__ __launch_bounds__(512, 2) void k_gemm256(
    const bf16* __restrict__ A, int lda, long az,
    const bf16* __restrict__ W, long wz,
    const float* __restrict__ bias, long bz,
    float* __restrict__ Cf, int ldcf, long cfz,
    bf16* __restrict__ Cb, int ldcb, long cbz,
    int K, int nN)
{
    __shared__ char lds[131072];
    const int tid = threadIdx.x;
    const int wid = tid >> 6, lane = tid & 63;
    const int z = blockIdx.z;
    const int fid = xcd_swz(blockIdx.x, gridDim.x);
    const int m0 = (fid / nN) * 256;
    const int n0 = (fid % nN) * 256;
    const int wr = wid >> 2, wc = wid & 3;

    const int srow = tid >> 2;
    const int sk   = ((tid & 3) ^ (srow & 3)) * 8;
    const bf16* Ag = A + (long)z * az + (long)(m0 + srow) * lda + sk;
    const bf16* Wg = W + (long)z * wz + (long)(n0 + srow) * K + sk;

    const int fr = lane & 15;
    const int xorv = (((lane >> 4) ^ (lane & 3)) << 4);
    const int aRd = wr * 16384 + fr * 64 + xorv;
    const int bRd = 65536 + (wc >> 1) * 16384 + ((wc & 1) << 12) + fr * 64 + xorv;

    f32x4 acc[8][4] = {};
    const int NT = K >> 6;

    auto issueA = [&](int db, int kh, int kb) {
        char* l = lds + db * 32768 + kh * 8192 + wid * 1024;
        gload_lds16(Ag + kb + kh * 32, l);
        gload_lds16(Ag + kb + kh * 32 + (long)128 * lda, l + 16384);
    };
    auto issueB = [&](int db, int kh, int kb) {
        char* l = lds + 65536 + db * 32768 + kh * 8192 + wid * 1024;
        gload_lds16(Wg + kb + kh * 32, l);
        gload_lds16(Wg + kb + kh * 32 + (long)128 * K, l + 16384);
    };

    // prologue: tile 0 -> buf 0, kh0 first (vmcnt ordering).
    issueA(0, 0, 0); issueB(0, 0, 0);
    issueA(0, 1, 0); issueB(0, 1, 0);
    WAITV4_BAR();     // kh0 A+B landed; kh1 (4) in flight

    for (int t = 0; t < NT; ++t) {
        const int db = t & 1, nb = db ^ 1;
        const int kn = (t + 1) << 6;
        const bool pf = (t + 1 < NT);
        const int abase = aRd + db * 32768;
        const int bbase = bRd + db * 32768;
        s16x8 a[4], b[4];

        // ---- phase 0: kk=0, mi 0-3; issue whole next tile ----
#pragma unroll
        for (int i = 0; i < 4; ++i) b[i] = *(const s16x8*)(lds + bbase + i * 1024);
#pragma unroll
        for (int i = 0; i < 4; ++i) a[i] = *(const s16x8*)(lds + abase + i * 1024);
        if (pf) {
            issueA(nb, 0, kn); issueB(nb, 0, kn);
            issueA(nb, 1, kn); issueB(nb, 1, kn);
        }
        BAR();
        __builtin_amdgcn_s_setprio(1);
#pragma unroll
        for (int mi = 0; mi < 4; ++mi)
#pragma unroll
            for (int ni = 0; ni < 4; ++ni)
                acc[mi][ni] = __builtin_amdgcn_mfma_f32_16x16x32_bf16(a[mi], b[ni], acc[mi][ni], 0, 0, 0);
        __builtin_amdgcn_s_setprio(0);
        BAR();

        // ---- phase 1: kk=0, mi 4-7 ----
#pragma unroll
        for (int i = 0; i < 4; ++i) a[i] = *(const s16x8*)(lds + abase + (4 + i) * 1024);
        BAR();
        __builtin_amdgcn_s_setprio(1);
#pragma unroll
        for (int mi = 0; mi < 4; ++mi)
#pragma unroll
            for (int ni = 0; ni < 4; ++ni)
                acc[4 + mi][ni] = __builtin_amdgcn_mfma_f32_16x16x32_bf16(a[mi], b[ni], acc[4 + mi][ni], 0, 0, 0);
        __builtin_amdgcn_s_setprio(0);
        if (pf) { WAITV8_BAR(); }    // t's kh1 landed (8 = next tile's loads stay in flight)
        else    { WAITV0_BAR(); }

        // ---- phase 2: kk=1, mi 0-3 ----
#pragma unroll
        for (int i = 0; i < 4; ++i) b[i] = *(const s16x8*)(lds + bbase + 8192 + i * 1024);
#pragma unroll
        for (int i = 0; i < 4; ++i) a[i] = *(const s16x8*)(lds + abase + 8192 + i * 1024);
        BAR();
        __builtin_amdgcn_s_setprio(1);
#pragma unroll
        for (int mi = 0; mi < 4; ++mi)
#pragma unroll
            for (int ni = 0; ni < 4; ++ni)
                acc[mi][ni] = __builtin_amdgcn_mfma_f32_16x16x32_bf16(a[mi], b[ni], acc[mi][ni], 0, 0, 0);
        __builtin_amdgcn_s_setprio(0);
        BAR();

        // ---- phase 3: kk=1, mi 4-7 ----
#pragma unroll
        for (int i = 0; i < 4; ++i) a[i] = *(const s16x8*)(lds + abase + 8192 + (4 + i) * 1024);
        BAR();
        __builtin_amdgcn_s_setprio(1);
#pragma unroll
        for (int mi = 0; mi < 4; ++mi)
#pragma unroll
            for (int ni = 0; ni < 4; ++ni)
                acc[4 + mi][ni] = __builtin_amdgcn_mfma_f32_16x16x32_bf16(a[mi], b[ni], acc[4 + mi][ni], 0, 0, 0);
        __builtin_amdgcn_s_setprio(0);
        if (pf) { WAITV4_BAR(); }    // t+1's kh0 landed; kh1 (4) stays in flight
    }

    const int rb = (lane >> 4) * 4;
#pragma unroll
    for (int ni = 0; ni < 4; ++ni) {
        const int col = n0 + wc * 64 + ni * 16 + fr;
        const float bv = bias[(long)z * bz + col];
#pragma unroll
        for (int mi = 0; mi < 8; ++mi) {
#pragma unroll
            for (int r = 0; r < 4; ++r) {
                const int row = m0 + wr * 128 + mi * 16 + rb + r;
                float v = acc[mi][ni][r] + bv;
                if (ACT == 1) v = fmaxf(v, 0.f);
                if (ACT == 2) v = v / (1.f + __expf(-v));
                if (OUTF) Cf[(long)z * cfz + (long)row * ldcf + col] = v;
                if (OUTB) Cb[(long)z * cbz + (long)row * ldcb + col] = to_bf16(v);
            }
        }
    }
}

// ================= 128x128 m97-style GEMM (N=1024 chain shapes) =================
// ldb = W row stride (may exceed K for sub-views). ADD: fp32 [M][1024] epilogue addend.
template<int ACT, int SEG, int ADD>
__global__ __launch_bounds__(256) void k_gemm(
    const bf16* __restrict__ A0, const bf16* __restrict__ A1, const bf16* __restrict__ A2,
    long az,
    const bf16* __restrict__ W, int ldb, long wz,
    const float* __restrict__ bias, long bz,
    const float* __restrict__ Add,
    float* __restrict__ Cf, int ldcf, long cfz,
    bf16* __restrict__ Cb, int ldcb, long cbz,
    int K, int nM)
{
    __shared__ bf16 As[128 * 32];
    __shared__ bf16 Bs[128 * 32];
    const int tid  = threadIdx.x;
    const int wid  = tid >> 6;
    const int lane = tid & 63;
    const int z  = blockIdx.z;

    const int fid = xcd_swz(blockIdx.x, gridDim.x);
    const int m0 = (fid % nM) * 128;
    const int n0 = (fid / nM) * 128;

    const int srow = tid >> 2;
    const int scol = (tid & 3) * 8;
    const long arow = (long)(m0 + srow) * 1024 + scol;
    const bf16* a0 = A0 + (long)z * az + arow;
    const bf16* a1 = SEG ? (A1 + arow) : nullptr;
    const bf16* a2 = SEG ? (A2 + arow) : nullptr;
    const bf16* bg = W + (long)z * wz + (long)(n0 + srow) * ldb + scol;

    char* asb = (char*)As;
    char* bsb = (char*)Bs;

    f32x4 acc[4][4] = {};

    const int wm = (wid >> 1) * 64;
    const int wn = (wid & 1) * 64;
    const int fr = lane & 15;
    const int kq = (lane >> 4) * 8;

    for (int k0 = 0; k0 < K; k0 += 32) {
        const bf16* ap;
        if (SEG) {
            const int seg = k0 >> 10, ko = k0 & 1023;
            ap = (seg == 0 ? a0 : (seg == 1 ? a1 : a2)) + ko;
        } else {
            ap = a0 + k0;
        }
        const bf16* bp = bg + k0;

        __syncthreads();
        gload_lds16(ap,                   asb + wid * 1024);
        gload_lds16(ap + 64 * 1024,       asb + 4096 + wid * 1024);
        gload_lds16(bp,                   bsb + wid * 1024);
        gload_lds16(bp + (long)64 * ldb,  bsb + 4096 + wid * 1024);
        __syncthreads();

        s16x8 af[4], bfv[4];
#pragma unroll
        for (int i = 0; i < 4; ++i)
            af[i] = *(const s16x8*)(As + (wm + i * 16 + fr) * 32 + kq);
#pragma unroll
        for (int i = 0; i < 4; ++i)
            bfv[i] = *(const s16x8*)(Bs + (wn + i * 16 + fr) * 32 + kq);
#pragma unroll
        for (int mi = 0; mi < 4; ++mi)
#pragma unroll
            for (int ni = 0; ni < 4; ++ni)
                acc[mi][ni] = __builtin_amdgcn_mfma_f32_16x16x32_bf16(
                    af[mi], bfv[ni], acc[mi][ni], 0, 0, 0);
    }

    const int rb = (lane >> 4) * 4;
#pragma unroll
    for (int ni = 0; ni < 4; ++ni) {
        const int col = n0 + wn + ni * 16 + fr;
        const float bv = bias ? bias[(long)z * bz + col] : 0.f;
#pragma unroll
        for (int mi = 0; mi < 4; ++mi) {
#pragma unroll
            for (int r = 0; r < 4; ++r) {
                const int row = m0 + wm + mi * 16 + rb + r;
                float v = acc[mi][ni][r] + bv;
                if (ADD) v += Add[(long)row * 1024 + col];
                if (ACT == 1) v = fmaxf(v, 0.f);
                if (ACT == 2) v = v / (1.f + __expf(-v));
                if (Cf) Cf[(long)z * cfz + (long)row * ldcf + col] = v;
                if (Cb) Cb[(long)z * cbz + (long)row * ldcb + col] = to_bf16(v);
            }
        }
    }
}

// ---------------- fused mask head ----------------
__global__ __launch_bounds__(64) void k_mask_softmax(
    const bf16* __restrict__ t, const float* __restrict__ W2,
    const float* __restrict__ b2, float* __restrict__ mask_out)
{
    const int tok = blockIdx.x;
    const int lane = threadIdx.x;
    float part[16];
#pragma unroll
    for (int e = 0; e < 16; ++e) part[e] = 0.f;
    const bf16* tr = t + (long)tok * 1024 + lane * 16;
#pragma unroll
    for (int kk = 0; kk < 16; ++kk) {
        float x = __bfloat162float(tr[kk]);
        const float* wr = W2 + (long)(lane * 16 + kk) * 16;
#pragma unroll
        for (int e = 0; e < 16; ++e) part[e] += x * wr[e];
    }
#pragma unroll
    for (int e = 0; e < 16; ++e) {
#pragma unroll
        for (int off = 32; off >= 1; off >>= 1)
            part[e] += __shfl_down(part[e], off);
    }
    if (lane == 0) {
        float vals[16], mx = -1e30f;
#pragma unroll
        for (int e = 0; e < 16; ++e) { vals[e] = part[e] + b2[e]; mx = fmaxf(mx, vals[e]); }
        float s = 0.f;
#pragma unroll
        for (int e = 0; e < 16; ++e) { vals[e] = __expf(vals[e] - mx); s += vals[e]; }
        float inv = 1.f / s;
#pragma unroll
        for (int e = 0; e < 16; ++e) mask_out[tok * 16 + e] = vals[e] * inv;
    }
}

// ---------------- qk = sum_e mask[tok][e] * EO[tok][e][:] -> bf16 ----------------
__global__ void k_qk(const float* __restrict__ EO, const float* __restrict__ mask,
                     bf16* __restrict__ qkb)
{
    int i = blockIdx.x * blockDim.x + threadIdx.x;
    int tok = i >> 8;
    int d4  = (i & 255) << 2;
    const float* eo = EO + (long)tok * 16384 + d4;
    const float* mk = mask + tok * 16;
    float4 s = make_float4(0.f, 0.f, 0.f, 0.f);
#pragma unroll
    for (int e = 0; e < 16; ++e) {
        float m = mk[e];
        float4 v = *(const float4*)(eo + e * 1024);
        s.x += m * v.x; s.y += m * v.y; s.z += m * v.z; s.w += m * v.w;
    }
    bf16x4_pack o{to_bf16(s.x), to_bf16(s.y), to_bf16(s.z), to_bf16(s.w)};
    ((bf16x4_pack*)qkb)[i] = o;
}

extern "C" void kernel_launch(void* const* d_in, const int* in_sizes, int n_in,
                              void* d_out, int out_size, void* d_ws, size_t ws_size,
                              hipStream_t stream)
{
    const int Mtok = 4096, D = 1024, E = 16, V = 32000, DIN = 3072;

    const float* L      = (const float*)d_in[0];
    const float* mL     = (const float*)d_in[1];
    const float* prompt = (const float*)d_in[2];
    const float* noise  = (const float*)d_in[3];
    const float* qa_W1 = (const float*)d_in[4];  const float* qa_b1 = (const float*)d_in[5];
    const float* qa_W2 = (const float*)d_in[6];  const float* qa_b2 = (const float*)d_in[7];
    const float* qb_W1 = (const float*)d_in[8];  const float* qb_b1 = (const float*)d_in[9];
    const float* qb_W2 = (const float*)d_in[10]; const float* qb_b2 = (const float*)d_in[11];
    const float* qc_W1 = (const float*)d_in[12]; const float* qc_b1 = (const float*)d_in[13];
    const float* qc_W2 = (const float*)d_in[14]; const float* qc_b2 = (const float*)d_in[15];
    const float* ek_W1 = (const float*)d_in[16]; const float* ek_b1 = (const float*)d_in[17];
    const float* ek_W2 = (const float*)d_in[18]; const float* ek_b2 = (const float*)d_in[19];
    const float* md_W1 = (const float*)d_in[20]; const float* md_b1 = (const float*)d_in[21];
    const float* md_W2 = (const float*)d_in[22]; const float* md_b2 = (const float*)d_in[23];
    const float* td_W  = (const float*)d_in[24]; const float* td_b  = (const float*)d_in[25];

    float* out = (float*)d_out;
    float* out_L2   = out;
    float* out_mLp  = out + 4194304;
    float* out_mask = out + 8388608;
    float* out_txt  = out + 8454144;
    float* out_EO   = out + 139526144;

    char* ws = (char*)d_ws;
    size_t off = 0;
    auto alloc = [&](size_t bytes) -> void* {
        void* p = ws + off;
        off += (bytes + 255) & ~(size_t)255;
        return p;
    };

    bf16* wqa1 = (bf16*)alloc((size_t)DIN * D * 2);
    bf16* wqa2 = (bf16*)alloc((size_t)D * D * 2);
    bf16* wqb1 = (bf16*)alloc((size_t)DIN * D * 2);
    bf16* wqb2 = (bf16*)alloc((size_t)D * D * 2);
    bf16* wqc1 = (bf16*)alloc((size_t)DIN * D * 2);
    bf16* wqc2 = (bf16*)alloc((size_t)D * D * 2);
    bf16* wmd1 = (bf16*)alloc((size_t)D * D * 2);
    bf16* wek1 = (bf16*)alloc((size_t)E * D * D * 2);
    bf16* wek2 = (bf16*)alloc((size_t)E * D * D * 2);
    bf16* wtd  = (bf16*)alloc((size_t)D * V * 2);

    bf16* Lb   = (bf16*)alloc((size_t)Mtok * D * 2);
    bf16* mLb  = (bf16*)alloc((size_t)Mtok * D * 2);
    bf16* Pb   = (bf16*)alloc((size_t)Mtok * D * 2);
    bf16* Nb   = (bf16*)alloc((size_t)Mtok * D * 2);
    bf16* hbuf = (bf16*)alloc((size_t)Mtok * D * 2);
    bf16* L1b  = (bf16*)alloc((size_t)Mtok * D * 2);
    bf16* sLb  = (bf16*)alloc((size_t)Mtok * D * 2);
    bf16* tb   = (bf16*)alloc((size_t)Mtok * D * 2);
    bf16* qkb  = (bf16*)alloc((size_t)Mtok * D * 2);
    bf16* L2b  = (bf16*)alloc((size_t)Mtok * D * 2);
    float* paf = (float*)alloc((size_t)Mtok * D * 4);   // qa shared partial (fp32)

    const size_t hall_bytes = (size_t)E * Mtok * D * 2;
    bool batched = (off + hall_bytes + 256 <= ws_size);
    bf16* hall = batched ? (bf16*)alloc(hall_bytes) : nullptr;

    auto conv = [&](const float* src, bf16* dst, long n) {
        int n4 = (int)(n / 4);
        k_conv_f32_bf16<<<dim3((n4 + 255) / 256), dim3(256), 0, stream>>>(src, dst, n4);
    };
    conv(L, Lb, (long)Mtok * D);
    conv(mL, mLb, (long)Mtok * D);
    conv(prompt, Pb, (long)Mtok * D);
    conv(noise, Nb, (long)Mtok * D);

    auto transp = [&](const float* src, bf16* dst, int K, int N, int Z, long inz, long outz) {
        dim3 g(N / 32, K / 32, Z);
        k_transpose_f32_bf16<<<g, dim3(256), 0, stream>>>(src, dst, K, N, inz, outz);
    };
    transp(qa_W1, wqa1, DIN, D, 1, 0, 0);
    transp(qa_W2, wqa2, D, D, 1, 0, 0);
    transp(qb_W1, wqb1, DIN, D, 1, 0, 0);
    transp(qb_W2, wqb2, D, D, 1, 0, 0);
    transp(qc_W1, wqc1, DIN, D, 1, 0, 0);
    transp(qc_W2, wqc2, D, D, 1, 0, 0);
    transp(md_W1, wmd1, D, D, 1, 0, 0);
    transp(ek_W1, wek1, D, D, 16, (long)D * D, (long)D * D);
    transp(ek_W2, wek2, D, D, 16, (long)D * D, (long)D * D);
    transp(td_W,  wtd,  D, V, 1, 0, 0);

    dim3 b128(256);
    const int nM = Mtok / 128;                 // 32
    dim3 g128(nM * (D / 128), 1, 1);           // 256 WGs for N=1024

    // pa = prompt @ qaW1b + mL @ qaW1c   (K=2048, fp32 out, no bias/act)
    k_gemm<0, 1, 0><<<g128, b128, 0, stream>>>(
        Pb, mLb, mLb, 0, wqa1 + 1024, DIN, 0, nullptr, 0, nullptr,
        paf, D, 0, nullptr, 0, 0, 2048, nM);

    // L1 = qa([L | prompt | mL]) : h = relu(L@W1a + pa + b1); L1 = h@W2 + b2
    k_gemm<1, 0, 1><<<g128, b128, 0, stream>>>(
        Lb, Lb, Lb, 0, wqa1, DIN, 0, qa_b1, 0, paf,
        nullptr, 0, 0, hbuf, D, 0, 1024, nM);
    k_gemm<0, 0, 0><<<g128, b128, 0, stream>>>(
        hbuf, hbuf, hbuf, 0, wqa2, D, 0, qa_b2, 0, nullptr,
        nullptr, 0, 0, L1b, D, 0, 1024, nM);

    // sL = qb([noise | prompt | L1])
    k_gemm<1, 1, 0><<<g128, b128, 0, stream>>>(
        Nb, Pb, L1b, 0, wqb1, DIN, 0, qb_b1, 0, nullptr,
        nullptr, 0, 0, hbuf, D, 0, DIN, nM);
    k_gemm<0, 0, 0><<<g128, b128, 0, stream>>>(
        hbuf, hbuf, hbuf, 0, wqb2, D, 0, qb_b2, 0, nullptr,
        nullptr, 0, 0, sLb, D, 0, 1024, nM);

    // mask = softmax(relu(sL @ md_W1 + b1) @ md_W2 + b2)
    k_gemm<1, 0, 0><<<g128, b128, 0, stream>>>(
        sLb, sLb, sLb, 0, wmd1, D, 0, md_b1, 0, nullptr,
        nullptr, 0, 0, tb, D, 0, 1024, nM);
    k_mask_softmax<<<dim3(Mtok), dim3(64), 0, stream>>>(tb, md_W2, md_b2, out_mask);

    // experts via deep 256^2 kernel (z=16)
    if (batched) {
        dim3 ge(16 * 4, 1, 16), be(512);
        k_gemm256<2, 0, 1><<<ge, be, 0, stream>>>(
            L1b, D, 0, wek1, (long)D * D, ek_b1, D,
            nullptr, 0, 0, hall, D, (long)Mtok * D, D, 4);
        k_gemm256<0, 1, 0><<<ge, be, 0, stream>>>(
            hall, D, (long)Mtok * D, wek2, (long)D * D, ek_b2, D,
            out_EO, E * D, D, nullptr, 0, 0, D, 4);
    } else {
        for (int e = 0; e < 16; ++e) {
            k_gemm<2, 0, 0><<<g128, b128, 0, stream>>>(
                L1b, L1b, L1b, 0, wek1 + (size_t)e * D * D, D, 0, ek_b1 + e * D, 0, nullptr,
                nullptr, 0, 0, hbuf, D, 0, 1024, nM);
            k_gemm<0, 0, 0><<<g128, b128, 0, stream>>>(
                hbuf, hbuf, hbuf, 0, wek2 + (size_t)e * D * D, D, 0, ek_b2 + e * D, 0, nullptr,
                out_EO + e * D, E * D, 0, nullptr, 0, 0, 1024, nM);
        }
    }

    // qk = sum_e mask * EO
    k_qk<<<dim3(4096), dim3(256), 0, stream>>>(out_EO, out_mask, qkb);

    // L2 = qa([qk | prompt | mL]) : h = relu(qk@W1a + pa + b1); L2 = h@W2 + b2
    k_gemm<1, 0, 1><<<g128, b128, 0, stream>>>(
        qkb, qkb, qkb, 0, wqa1, DIN, 0, qa_b1, 0, paf,
        nullptr, 0, 0, hbuf, D, 0, 1024, nM);
    k_gemm<0, 0, 0><<<g128, b128, 0, stream>>>(
        hbuf, hbuf, hbuf, 0, wqa2, D, 0, qa_b2, 0, nullptr,
        out_L2, D, 0, L2b, D, 0, 1024, nM);

    // mL_pred = qc([mL | prompt | L2])
    k_gemm<1, 1, 0><<<g128, b128, 0, stream>>>(
        mLb, Pb, L2b, 0, wqc1, DIN, 0, qc_b1, 0, nullptr,
        nullptr, 0, 0, hbuf, D, 0, DIN, nM);
    k_gemm<0, 0, 0><<<g128, b128, 0, stream>>>(
        hbuf, hbuf, hbuf, 0, wqc2, D, 0, qc_b2, 0, nullptr,
        out_mLp, D, 0, nullptr, 0, 0, 1024, nM);

    // text_logits = L2 @ td_W + td_b  (deep 256^2)
    {
        dim3 gl(16 * 125, 1, 1), bl(512);
        k_gemm256<0, 1, 0><<<gl, bl, 0, stream>>>(
            L2b, D, 0, wtd, 0, td_b, 0,
            out_txt, V, 0, nullptr, 0, 0, D, 125);
    }
}

// Round 5
// 1359.038 us; speedup vs baseline: 1.2146x; 1.2146x over previous
//
#include <hip/hip_runtime.h>
#include <hip/hip_bf16.h>
#include <cstdint>
#include <cstddef>

using bf16 = __hip_bfloat16;

typedef __attribute__((ext_vector_type(4))) float f32x4;
typedef __attribute__((ext_vector_type(8))) short s16x8;

__device__ __forceinline__ bf16 to_bf16(float v) { return __float2bfloat16(v); }

struct alignas(8) bf16x4_pack { bf16 x, y, z, w; };

// bijective XCD-chunking swizzle (m204)
__device__ __forceinline__ int xcd_swz(int orig, int nwg) {
    int xcd = orig & 7, base = orig >> 3;
    int q = nwg >> 3, r = nwg & 7;
    return (xcd < r ? xcd * (q + 1) : r * (q + 1) + (xcd - r) * q) + base;
}

#define BAR()        asm volatile("s_barrier" ::: "memory")
#define WAITV4_BAR() asm volatile("s_waitcnt vmcnt(4)\ns_barrier" ::: "memory")
#define WAITV0_BAR() asm volatile("s_waitcnt vmcnt(0)\ns_barrier" ::: "memory")

// ---------------- fp32 -> bf16 elementwise ----------------
__global__ void k_conv_f32_bf16(const float* __restrict__ in, bf16* __restrict__ out, int n4) {
    int i = blockIdx.x * blockDim.x + threadIdx.x;
    if (i >= n4) return;
    float4 v = ((const float4*)in)[i];
    bf16x4_pack o{to_bf16(v.x), to_bf16(v.y), to_bf16(v.z), to_bf16(v.w)};
    ((bf16x4_pack*)out)[i] = o;
}

// ---------------- fp32 [K][N] -> bf16 [N][K] tiled transpose ----------------
__global__ __launch_bounds__(256) void k_transpose_f32_bf16(
    const float* __restrict__ in, bf16* __restrict__ out,
    int K, int N, long inz, long outz)
{
    __shared__ float t[32][33];
    in  += (long)blockIdx.z * inz;
    out += (long)blockIdx.z * outz;
    int n0 = blockIdx.x * 32, k0 = blockIdx.y * 32;
    int tx = threadIdx.x & 31, ty = threadIdx.x >> 5;
#pragma unroll
    for (int r = 0; r < 32; r += 8)
        t[ty + r][tx] = in[(long)(k0 + ty + r) * N + (n0 + tx)];
    __syncthreads();
#pragma unroll
    for (int r = 0; r < 32; r += 8)
        out[(long)(n0 + ty + r) * K + (k0 + tx)] = to_bf16(t[tx][ty + r]);
}

// ---------------- async global->LDS 16B helper ----------------
__device__ __forceinline__ void gload_lds16(const void* g, void* l) {
    __builtin_amdgcn_global_load_lds(
        (const __attribute__((address_space(1))) void*)g,
        (__attribute__((address_space(3))) void*)l,
        16, 0, 0);
}

// ================= 256x256 BK=64 8-wave phased GEMM (round-3 proven cadence) =================
// Schedule per K-tile: ph0 issue A(kh0), ph1 issue B(kh0) + WAITV4; ph2 issue A(kh1),
// ph3 issue B(kh1) + WAITV4. Swizzle k16' = k16 ^ (row&3) both-sides (rule #21).
template<int ACT, int OUTF, int OUTB>   // ACT: 0 none, 1 relu, 2 silu
__global__ __launch_bounds__(512, 2) void k_gemm256(
    const bf16* __restrict__ A, int lda, long az,
    const bf16* __restrict__ W, long wz,
    const float* __restrict__ bias, long bz,
    float* __restrict__ Cf, int ldcf, long cfz,
    bf16* __restrict__ Cb, int ldcb, long cbz,
    int K, int nN)
{
    __shared__ char lds[131072];
    const int tid = threadIdx.x;
    const int wid = tid >> 6, lane = tid & 63;
    const int z = blockIdx.z;
    const int fid = xcd_swz(blockIdx.x, gridDim.x);
    const int m0 = (fid / nN) * 256;
    const int n0 = (fid % nN) * 256;
    const int wr = wid >> 2, wc = wid & 3;

    const int srow = tid >> 2;
    const int sk   = ((tid & 3) ^ (srow & 3)) * 8;
    const bf16* Ag = A + (long)z * az + (long)(m0 + srow) * lda + sk;
    const bf16* Wg = W + (long)z * wz + (long)(n0 + srow) * K + sk;

    const int fr = lane & 15;
    const int xorv = (((lane >> 4) ^ (lane & 3)) << 4);
    const int aRd = wr * 16384 + fr * 64 + xorv;
    const int bRd = 65536 + (wc >> 1) * 16384 + ((wc & 1) << 12) + fr * 64 + xorv;

    f32x4 acc[8][4] = {};
    const int NT = K >> 6;

    auto issueA = [&](int db, int kh, int kb) {
        char* l = lds + db * 32768 + kh * 8192 + wid * 1024;
        gload_lds16(Ag + kb + kh * 32, l);
        gload_lds16(Ag + kb + kh * 32 + (long)128 * lda, l + 16384);
    };
    auto issueB = [&](int db, int kh, int kb) {
        char* l = lds + 65536 + db * 32768 + kh * 8192 + wid * 1024;
        gload_lds16(Wg + kb + kh * 32, l);
        gload_lds16(Wg + kb + kh * 32 + (long)128 * K, l + 16384);
    };

    issueA(0, 0, 0); issueB(0, 0, 0);
    issueA(0, 1, 0); issueB(0, 1, 0);
    WAITV4_BAR();     // kh0 A+B landed

    for (int t = 0; t < NT; ++t) {
        const int db = t & 1, nb = db ^ 1;
        const int kn = (t + 1) << 6;
        const bool pf = (t + 1 < NT);
        const int abase = aRd + db * 32768;
        const int bbase = bRd + db * 32768;
        s16x8 a[4], b[4];

        // ---- phase 0: kk=0, mi 0-3 ----
#pragma unroll
        for (int i = 0; i < 4; ++i) b[i] = *(const s16x8*)(lds + bbase + i * 1024);
#pragma unroll
        for (int i = 0; i < 4; ++i) a[i] = *(const s16x8*)(lds + abase + i * 1024);
        if (pf) issueA(nb, 0, kn);
        BAR();
        __builtin_amdgcn_s_setprio(1);
#pragma unroll
        for (int mi = 0; mi < 4; ++mi)
#pragma unroll
            for (int ni = 0; ni < 4; ++ni)
                acc[mi][ni] = __builtin_amdgcn_mfma_f32_16x16x32_bf16(a[mi], b[ni], acc[mi][ni], 0, 0, 0);
        __builtin_amdgcn_s_setprio(0);
        BAR();

        // ---- phase 1: kk=0, mi 4-7 ----
#pragma unroll
        for (int i = 0; i < 4; ++i) a[i] = *(const s16x8*)(lds + abase + (4 + i) * 1024);
        if (pf) issueB(nb, 0, kn);
        BAR();
        __builtin_amdgcn_s_setprio(1);
#pragma unroll
        for (int mi = 0; mi < 4; ++mi)
#pragma unroll
            for (int ni = 0; ni < 4; ++ni)
                acc[4 + mi][ni] = __builtin_amdgcn_mfma_f32_16x16x32_bf16(a[mi], b[ni], acc[4 + mi][ni], 0, 0, 0);
        __builtin_amdgcn_s_setprio(0);
        if (pf) { WAITV4_BAR(); }    // t's kh1 landed; (t+1, kh0) in flight
        else    { WAITV0_BAR(); }

        // ---- phase 2: kk=1, mi 0-3 ----
#pragma unroll
        for (int i = 0; i < 4; ++i) b[i] = *(const s16x8*)(lds + bbase + 8192 + i * 1024);
#pragma unroll
        for (int i = 0; i < 4; ++i) a[i] = *(const s16x8*)(lds + abase + 8192 + i * 1024);
        if (pf) issueA(nb, 1, kn);
        BAR();
        __builtin_amdgcn_s_setprio(1);
#pragma unroll
        for (int mi = 0; mi < 4; ++mi)
#pragma unroll
            for (int ni = 0; ni < 4; ++ni)
                acc[mi][ni] = __builtin_amdgcn_mfma_f32_16x16x32_bf16(a[mi], b[ni], acc[mi][ni], 0, 0, 0);
        __builtin_amdgcn_s_setprio(0);
        BAR();

        // ---- phase 3: kk=1, mi 4-7 ----
#pragma unroll
        for (int i = 0; i < 4; ++i) a[i] = *(const s16x8*)(lds + abase + 8192 + (4 + i) * 1024);
        if (pf) issueB(nb, 1, kn);
        BAR();
        __builtin_amdgcn_s_setprio(1);
#pragma unroll
        for (int mi = 0; mi < 4; ++mi)
#pragma unroll
            for (int ni = 0; ni < 4; ++ni)
                acc[4 + mi][ni] = __builtin_amdgcn_mfma_f32_16x16x32_bf16(a[mi], b[ni], acc[4 + mi][ni], 0, 0, 0);
        __builtin_amdgcn_s_setprio(0);
        if (pf) { WAITV4_BAR(); }    // (t+1, kh0) landed
    }

    const int rb = (lane >> 4) * 4;
#pragma unroll
    for (int ni = 0; ni < 4; ++ni) {
        const int col = n0 + wc * 64 + ni * 16 + fr;
        const float bv = bias[(long)z * bz + col];
#pragma unroll
        for (int mi = 0; mi < 8; ++mi) {
#pragma unroll
            for (int r = 0; r < 4; ++r) {
                const int row = m0 + wr * 128 + mi * 16 + rb + r;
                float v = acc[mi][ni][r] + bv;
                if (ACT == 1) v = fmaxf(v, 0.f);
                if (ACT == 2) v = v / (1.f + __expf(-v));
                if (OUTF) Cf[(long)z * cfz + (long)row * ldcf + col] = v;
                if (OUTB) Cb[(long)z * cbz + (long)row * ldcb + col] = to_bf16(v);
            }
        }
    }
}

// ================= 64x128 m97-style GEMM for the N=1024 chain =================
// 256 thr = 4 waves (2M x 2N), wave tile 32x64. 12KB LDS -> 2 blocks/CU at 512 WGs
// (vs 1 block/CU with 128^2): inter-block overlap hides the per-K-step barrier drain.
// ldb = W row stride. ADD: fp32 [M][1024] epilogue addend. A row stride fixed 1024.
template<int ACT, int SEG, int ADD>
__global__ __launch_bounds__(256, 4) void k_gemm64(
    const bf16* __restrict__ A0, const bf16* __restrict__ A1, const bf16* __restrict__ A2,
    const bf16* __restrict__ W, int ldb, long wz,
    const float* __restrict__ bias, long bz,
    const float* __restrict__ Add,
    float* __restrict__ Cf, int ldcf,
    bf16* __restrict__ Cb, int ldcb,
    int K, int nM)    // nM = M/64
{
    __shared__ bf16 As[64 * 32];
    __shared__ bf16 Bs[128 * 32];
    const int tid  = threadIdx.x;
    const int wid  = tid >> 6;
    const int lane = tid & 63;
    const int z = blockIdx.z;

    const int fid = xcd_swz(blockIdx.x, gridDim.x);
    const int m0 = (fid % nM) * 64;
    const int n0 = (fid / nM) * 128;

    const int srow = tid >> 2;
    const int scol = (tid & 3) * 8;
    const long arow = (long)(m0 + srow) * 1024 + scol;
    const bf16* a0 = A0 + arow;
    const bf16* a1 = SEG ? (A1 + arow) : nullptr;
    const bf16* a2 = SEG ? (A2 + arow) : nullptr;
    const bf16* bg = W + (long)z * wz + (long)(n0 + srow) * ldb + scol;

    char* asb = (char*)As;
    char* bsb = (char*)Bs;

    f32x4 acc[2][4] = {};

    const int wm = (wid >> 1) * 32;
    const int wn = (wid & 1) * 64;
    const int fr = lane & 15;
    const int kq = (lane >> 4) * 8;

    for (int k0 = 0; k0 < K; k0 += 32) {
        const bf16* ap;
        if (SEG) {
            const int seg = k0 >> 10, ko = k0 & 1023;
            ap = (seg == 0 ? a0 : (seg == 1 ? a1 : a2)) + ko;
        } else {
            ap = a0 + k0;
        }
        const bf16* bp = bg + k0;

        __syncthreads();
        gload_lds16(ap,                   asb + wid * 1024);
        gload_lds16(bp,                   bsb + wid * 1024);
        gload_lds16(bp + (long)64 * ldb,  bsb + 4096 + wid * 1024);
        __syncthreads();

        s16x8 af[2], bfv[4];
#pragma unroll
        for (int i = 0; i < 2; ++i)
            af[i] = *(const s16x8*)(As + (wm + i * 16 + fr) * 32 + kq);
#pragma unroll
        for (int i = 0; i < 4; ++i)
            bfv[i] = *(const s16x8*)(Bs + (wn + i * 16 + fr) * 32 + kq);
#pragma unroll
        for (int mi = 0; mi < 2; ++mi)
#pragma unroll
            for (int ni = 0; ni < 4; ++ni)
                acc[mi][ni] = __builtin_amdgcn_mfma_f32_16x16x32_bf16(
                    af[mi], bfv[ni], acc[mi][ni], 0, 0, 0);
    }

    const int rb = (lane >> 4) * 4;
#pragma unroll
    for (int ni = 0; ni < 4; ++ni) {
        const int col = n0 + wn + ni * 16 + fr;
        const float bv = bias ? bias[(long)z * bz + col] : 0.f;
#pragma unroll
        for (int mi = 0; mi < 2; ++mi) {
#pragma unroll
            for (int r = 0; r < 4; ++r) {
                const int row = m0 + wm + mi * 16 + rb + r;
                float v = acc[mi][ni][r] + bv;
                if (ADD) v += Add[(long)row * 1024 + col];
                if (ACT == 1) v = fmaxf(v, 0.f);
                if (ACT == 2) v = v / (1.f + __expf(-v));
                if (Cf) Cf[(long)row * ldcf + col] = v;
                if (Cb) Cb[(long)row * ldcb + col] = to_bf16(v);
            }
        }
    }
}

// ---------------- fused mask head ----------------
__global__ __launch_bounds__(64) void k_mask_softmax(
    const bf16* __restrict__ t, const float* __restrict__ W2,
    const float* __restrict__ b2, float* __restrict__ mask_out)
{
    const int tok = blockIdx.x;
    const int lane = threadIdx.x;
    float part[16];
#pragma unroll
    for (int e = 0; e < 16; ++e) part[e] = 0.f;
    const bf16* tr = t + (long)tok * 1024 + lane * 16;
#pragma unroll
    for (int kk = 0; kk < 16; ++kk) {
        float x = __bfloat162float(tr[kk]);
        const float* wr = W2 + (long)(lane * 16 + kk) * 16;
#pragma unroll
        for (int e = 0; e < 16; ++e) part[e] += x * wr[e];
    }
#pragma unroll
    for (int e = 0; e < 16; ++e) {
#pragma unroll
        for (int off = 32; off >= 1; off >>= 1)
            part[e] += __shfl_down(part[e], off);
    }
    if (lane == 0) {
        float vals[16], mx = -1e30f;
#pragma unroll
        for (int e = 0; e < 16; ++e) { vals[e] = part[e] + b2[e]; mx = fmaxf(mx, vals[e]); }
        float s = 0.f;
#pragma unroll
        for (int e = 0; e < 16; ++e) { vals[e] = __expf(vals[e] - mx); s += vals[e]; }
        float inv = 1.f / s;
#pragma unroll
        for (int e = 0; e < 16; ++e) mask_out[tok * 16 + e] = vals[e] * inv;
    }
}

// ---------------- qk = sum_e mask[tok][e] * EO[tok][e][:] -> bf16 ----------------
__global__ void k_qk(const float* __restrict__ EO, const float* __restrict__ mask,
                     bf16* __restrict__ qkb)
{
    int i = blockIdx.x * blockDim.x + threadIdx.x;
    int tok = i >> 8;
    int d4  = (i & 255) << 2;
    const float* eo = EO + (long)tok * 16384 + d4;
    const float* mk = mask + tok * 16;
    float4 s = make_float4(0.f, 0.f, 0.f, 0.f);
#pragma unroll
    for (int e = 0; e < 16; ++e) {
        float m = mk[e];
        float4 v = *(const float4*)(eo + e * 1024);
        s.x += m * v.x; s.y += m * v.y; s.z += m * v.z; s.w += m * v.w;
    }
    bf16x4_pack o{to_bf16(s.x), to_bf16(s.y), to_bf16(s.z), to_bf16(s.w)};
    ((bf16x4_pack*)qkb)[i] = o;
}

extern "C" void kernel_launch(void* const* d_in, const int* in_sizes, int n_in,
                              void* d_out, int out_size, void* d_ws, size_t ws_size,
                              hipStream_t stream)
{
    const int Mtok = 4096, D = 1024, E = 16, V = 32000, DIN = 3072;

    const float* L      = (const float*)d_in[0];
    const float* mL     = (const float*)d_in[1];
    const float* prompt = (const float*)d_in[2];
    const float* noise  = (const float*)d_in[3];
    const float* qa_W1 = (const float*)d_in[4];  const float* qa_b1 = (const float*)d_in[5];
    const float* qa_W2 = (const float*)d_in[6];  const float* qa_b2 = (const float*)d_in[7];
    const float* qb_W1 = (const float*)d_in[8];  const float* qb_b1 = (const float*)d_in[9];
    const float* qb_W2 = (const float*)d_in[10]; const float* qb_b2 = (const float*)d_in[11];
    const float* qc_W1 = (const float*)d_in[12]; const float* qc_b1 = (const float*)d_in[13];
    const float* qc_W2 = (const float*)d_in[14]; const float* qc_b2 = (const float*)d_in[15];
    const float* ek_W1 = (const float*)d_in[16]; const float* ek_b1 = (const float*)d_in[17];
    const float* ek_W2 = (const float*)d_in[18]; const float* ek_b2 = (const float*)d_in[19];
    const float* md_W1 = (const float*)d_in[20]; const float* md_b1 = (const float*)d_in[21];
    const float* md_W2 = (const float*)d_in[22]; const float* md_b2 = (const float*)d_in[23];
    const float* td_W  = (const float*)d_in[24]; const float* td_b  = (const float*)d_in[25];

    float* out = (float*)d_out;
    float* out_L2   = out;
    float* out_mLp  = out + 4194304;
    float* out_mask = out + 8388608;
    float* out_txt  = out + 8454144;
    float* out_EO   = out + 139526144;

    char* ws = (char*)d_ws;
    size_t off = 0;
    auto alloc = [&](size_t bytes) -> void* {
        void* p = ws + off;
        off += (bytes + 255) & ~(size_t)255;
        return p;
    };

    bf16* wqa1 = (bf16*)alloc((size_t)DIN * D * 2);
    bf16* wqa2 = (bf16*)alloc((size_t)D * D * 2);
    bf16* wqb1 = (bf16*)alloc((size_t)DIN * D * 2);
    bf16* wqb2 = (bf16*)alloc((size_t)D * D * 2);
    bf16* wqc1 = (bf16*)alloc((size_t)DIN * D * 2);
    bf16* wqc2 = (bf16*)alloc((size_t)D * D * 2);
    bf16* wmd1 = (bf16*)alloc((size_t)D * D * 2);
    bf16* wek1 = (bf16*)alloc((size_t)E * D * D * 2);
    bf16* wek2 = (bf16*)alloc((size_t)E * D * D * 2);
    bf16* wtd  = (bf16*)alloc((size_t)D * V * 2);

    bf16* Lb   = (bf16*)alloc((size_t)Mtok * D * 2);
    bf16* mLb  = (bf16*)alloc((size_t)Mtok * D * 2);
    bf16* Pb   = (bf16*)alloc((size_t)Mtok * D * 2);
    bf16* Nb   = (bf16*)alloc((size_t)Mtok * D * 2);
    bf16* hbuf = (bf16*)alloc((size_t)Mtok * D * 2);
    bf16* L1b  = (bf16*)alloc((size_t)Mtok * D * 2);
    bf16* sLb  = (bf16*)alloc((size_t)Mtok * D * 2);
    bf16* tb   = (bf16*)alloc((size_t)Mtok * D * 2);
    bf16* qkb  = (bf16*)alloc((size_t)Mtok * D * 2);
    bf16* L2b  = (bf16*)alloc((size_t)Mtok * D * 2);
    float* paf = (float*)alloc((size_t)Mtok * D * 4);   // qa shared partial (fp32)

    const size_t hall_bytes = (size_t)E * Mtok * D * 2;
    bool batched = (off + hall_bytes + 256 <= ws_size);
    bf16* hall = batched ? (bf16*)alloc(hall_bytes) : nullptr;

    auto conv = [&](const float* src, bf16* dst, long n) {
        int n4 = (int)(n / 4);
        k_conv_f32_bf16<<<dim3((n4 + 255) / 256), dim3(256), 0, stream>>>(src, dst, n4);
    };
    conv(L, Lb, (long)Mtok * D);
    conv(mL, mLb, (long)Mtok * D);
    conv(prompt, Pb, (long)Mtok * D);
    conv(noise, Nb, (long)Mtok * D);

    auto transp = [&](const float* src, bf16* dst, int K, int N, int Z, long inz, long outz) {
        dim3 g(N / 32, K / 32, Z);
        k_transpose_f32_bf16<<<g, dim3(256), 0, stream>>>(src, dst, K, N, inz, outz);
    };
    transp(qa_W1, wqa1, DIN, D, 1, 0, 0);
    transp(qa_W2, wqa2, D, D, 1, 0, 0);
    transp(qb_W1, wqb1, DIN, D, 1, 0, 0);
    transp(qb_W2, wqb2, D, D, 1, 0, 0);
    transp(qc_W1, wqc1, DIN, D, 1, 0, 0);
    transp(qc_W2, wqc2, D, D, 1, 0, 0);
    transp(md_W1, wmd1, D, D, 1, 0, 0);
    transp(ek_W1, wek1, D, D, 16, (long)D * D, (long)D * D);
    transp(ek_W2, wek2, D, D, 16, (long)D * D, (long)D * D);
    transp(td_W,  wtd,  D, V, 1, 0, 0);

    dim3 b64(256);
    const int nM64 = Mtok / 64;                 // 64
    dim3 g64(nM64 * (D / 128), 1, 1);           // 512 WGs for N=1024

    // pa = prompt @ qaW1b + mL @ qaW1c   (K=2048, fp32 out, no bias/act)
    k_gemm64<0, 1, 0><<<g64, b64, 0, stream>>>(
        Pb, mLb, mLb, wqa1 + 1024, DIN, 0, nullptr, 0, nullptr,
        paf, D, nullptr, 0, 2048, nM64);

    // L1 = qa([L | prompt | mL]) : h = relu(L@W1a + pa + b1); L1 = h@W2 + b2
    k_gemm64<1, 0, 1><<<g64, b64, 0, stream>>>(
        Lb, Lb, Lb, wqa1, DIN, 0, qa_b1, 0, paf,
        nullptr, 0, hbuf, D, 1024, nM64);
    k_gemm64<0, 0, 0><<<g64, b64, 0, stream>>>(
        hbuf, hbuf, hbuf, wqa2, D, 0, qa_b2, 0, nullptr,
        nullptr, 0, L1b, D, 1024, nM64);

    // sL = qb([noise | prompt | L1])
    k_gemm64<1, 1, 0><<<g64, b64, 0, stream>>>(
        Nb, Pb, L1b, wqb1, DIN, 0, qb_b1, 0, nullptr,
        nullptr, 0, hbuf, D, 3072, nM64);
    k_gemm64<0, 0, 0><<<g64, b64, 0, stream>>>(
        hbuf, hbuf, hbuf, wqb2, D, 0, qb_b2, 0, nullptr,
        nullptr, 0, sLb, D, 1024, nM64);

    // mask = softmax(relu(sL @ md_W1 + b1) @ md_W2 + b2)
    k_gemm64<1, 0, 0><<<g64, b64, 0, stream>>>(
        sLb, sLb, sLb, wmd1, D, 0, md_b1, 0, nullptr,
        nullptr, 0, tb, D, 1024, nM64);
    k_mask_softmax<<<dim3(Mtok), dim3(64), 0, stream>>>(tb, md_W2, md_b2, out_mask);

    // experts via 256^2 phased kernel (z=16)
    if (batched) {
        dim3 ge(16 * 4, 1, 16), be(512);
        k_gemm256<2, 0, 1><<<ge, be, 0, stream>>>(
            L1b, D, 0, wek1, (long)D * D, ek_b1, D,
            nullptr, 0, 0, hall, D, (long)Mtok * D, D, 4);
        k_gemm256<0, 1, 0><<<ge, be, 0, stream>>>(
            hall, D, (long)Mtok * D, wek2, (long)D * D, ek_b2, D,
            out_EO, E * D, D, nullptr, 0, 0, D, 4);
    } else {
        for (int e = 0; e < 16; ++e) {
            k_gemm64<2, 0, 0><<<g64, b64, 0, stream>>>(
                L1b, L1b, L1b, wek1 + (size_t)e * D * D, D, 0, ek_b1 + e * D, 0, nullptr,
                nullptr, 0, hbuf, D, 1024, nM64);
            k_gemm64<0, 0, 0><<<g64, b64, 0, stream>>>(
                hbuf, hbuf, hbuf, wek2 + (size_t)e * D * D, D, 0, ek_b2 + e * D, 0, nullptr,
                out_EO + e * D, E * D, nullptr, 0, 1024, nM64);
        }
    }

    // qk = sum_e mask * EO
    k_qk<<<dim3(4096), dim3(256), 0, stream>>>(out_EO, out_mask, qkb);

    // L2 = qa([qk | prompt | mL]) : h = relu(qk@W1a + pa + b1); L2 = h@W2 + b2
    k_gemm64<1, 0, 1><<<g64, b64, 0, stream>>>(
        qkb, qkb, qkb, wqa1, DIN, 0, qa_b1, 0, paf,
        nullptr, 0, hbuf, D, 1024, nM64);
    k_gemm64<0, 0, 0><<<g64, b64, 0, stream>>>(
        hbuf, hbuf, hbuf, wqa2, D, 0, qa_b2, 0, nullptr,
        out_L2, D, L2b, D, 1024, nM64);

    // mL_pred = qc([mL | prompt | L2])
    k_gemm64<1, 1, 0><<<g64, b64, 0, stream>>>(
        mLb, Pb, L2b, wqc1, DIN, 0, qc_b1, 0, nullptr,
        nullptr, 0, hbuf, D, 3072, nM64);
    k_gemm64<0, 0, 0><<<g64, b64, 0, stream>>>(
        hbuf, hbuf, hbuf, wqc2, D, 0, qc_b2, 0, nullptr,
        out_mLp, D, nullptr, 0, 1024, nM64);

    // text_logits = L2 @ td_W + td_b  (256^2 phased)
    {
        dim3 gl(16 * 125, 1, 1), bl(512);
        k_gemm256<0, 1, 0><<<gl, bl, 0, stream>>>(
            L2b, D, 0, wtd, 0, td_b, 0,
            out_txt, V, 0, nullptr, 0, 0, D, 125);
    }
}

// Round 7
// 1196.256 us; speedup vs baseline: 1.3799x; 1.1361x over previous
//
#include <hip/hip_runtime.h>
#include <hip/hip_bf16.h>
#include <cstdint>
#include <cstddef>

using bf16 = __hip_bfloat16;

typedef __attribute__((ext_vector_type(4))) float f32x4;
typedef __attribute__((ext_vector_type(8))) short s16x8;

__device__ __forceinline__ bf16 to_bf16(float v) { return __float2bfloat16(v); }

struct alignas(8) bf16x4_pack { bf16 x, y, z, w; };

// bijective XCD-chunking swizzle (m204)
__device__ __forceinline__ int xcd_swz(int orig, int nwg) {
    int xcd = orig & 7, base = orig >> 3;
    int q = nwg >> 3, r = nwg & 7;
    return (xcd < r ? xcd * (q + 1) : r * (q + 1) + (xcd - r) * q) + base;
}

#define BAR()        asm volatile("s_barrier" ::: "memory")
#define WAITV4_BAR() asm volatile("s_waitcnt vmcnt(4)\ns_barrier" ::: "memory")
#define WAITV0_BAR() asm volatile("s_waitcnt vmcnt(0)\ns_barrier" ::: "memory")

// ---------------- fp32 -> bf16 elementwise ----------------
__global__ void k_conv_f32_bf16(const float* __restrict__ in, bf16* __restrict__ out, int n4) {
    int i = blockIdx.x * blockDim.x + threadIdx.x;
    if (i >= n4) return;
    float4 v = ((const float4*)in)[i];
    bf16x4_pack o{to_bf16(v.x), to_bf16(v.y), to_bf16(v.z), to_bf16(v.w)};
    ((bf16x4_pack*)out)[i] = o;
}

// ---------------- fp32 [K][N] -> bf16 [N][K] tiled transpose ----------------
__global__ __launch_bounds__(256) void k_transpose_f32_bf16(
    const float* __restrict__ in, bf16* __restrict__ out,
    int K, int N, long inz, long outz)
{
    __shared__ float t[32][33];
    in  += (long)blockIdx.z * inz;
    out += (long)blockIdx.z * outz;
    int n0 = blockIdx.x * 32, k0 = blockIdx.y * 32;
    int tx = threadIdx.x & 31, ty = threadIdx.x >> 5;
#pragma unroll
    for (int r = 0; r < 32; r += 8)
        t[ty + r][tx] = in[(long)(k0 + ty + r) * N + (n0 + tx)];
    __syncthreads();
#pragma unroll
    for (int r = 0; r < 32; r += 8)
        out[(long)(n0 + ty + r) * K + (k0 + tx)] = to_bf16(t[tx][ty + r]);
}

// ---------------- async global->LDS 16B helper ----------------
__device__ __forceinline__ void gload_lds16(const void* g, void* l) {
    __builtin_amdgcn_global_load_lds(
        (const __attribute__((address_space(1))) void*)g,
        (__attribute__((address_space(3))) void*)l,
        16, 0, 0);
}

// ================= 256x256 BK=64 8-wave phased GEMM (round-3/5 proven cadence) =================
template<int ACT, int OUTF, int OUTB>   // ACT: 0 none, 1 relu, 2 silu
__global__ __launch_bounds__(512, 2) void k_gemm256(
    const bf16* __restrict__ A, int lda, long az,
    const bf16* __restrict__ W, long wz,
    const float* __restrict__ bias, long bz,
    float* __restrict__ Cf, int ldcf, long cfz,
    bf16* __restrict__ Cb, int ldcb, long cbz,
    int K, int nN)
{
    __shared__ char lds[131072];
    const int tid = threadIdx.x;
    const int wid = tid >> 6, lane = tid & 63;
    const int z = blockIdx.z;
    const int fid = xcd_swz(blockIdx.x, gridDim.x);
    const int m0 = (fid / nN) * 256;
    const int n0 = (fid % nN) * 256;
    const int wr = wid >> 2, wc = wid & 3;

    const int srow = tid >> 2;
    const int sk   = ((tid & 3) ^ (srow & 3)) * 8;
    const bf16* Ag = A + (long)z * az + (long)(m0 + srow) * lda + sk;
    const bf16* Wg = W + (long)z * wz + (long)(n0 + srow) * K + sk;

    const int fr = lane & 15;
    const int xorv = (((lane >> 4) ^ (lane & 3)) << 4);
    const int aRd = wr * 16384 + fr * 64 + xorv;
    const int bRd = 65536 + (wc >> 1) * 16384 + ((wc & 1) << 12) + fr * 64 + xorv;

    f32x4 acc[8][4] = {};
    const int NT = K >> 6;

    auto issueA = [&](int db, int kh, int kb) {
        char* l = lds + db * 32768 + kh * 8192 + wid * 1024;
        gload_lds16(Ag + kb + kh * 32, l);
        gload_lds16(Ag + kb + kh * 32 + (long)128 * lda, l + 16384);
    };
    auto issueB = [&](int db, int kh, int kb) {
        char* l = lds + 65536 + db * 32768 + kh * 8192 + wid * 1024;
        gload_lds16(Wg + kb + kh * 32, l);
        gload_lds16(Wg + kb + kh * 32 + (long)128 * K, l + 16384);
    };

    issueA(0, 0, 0); issueB(0, 0, 0);
    issueA(0, 1, 0); issueB(0, 1, 0);
    WAITV4_BAR();

    for (int t = 0; t < NT; ++t) {
        const int db = t & 1, nb = db ^ 1;
        const int kn = (t + 1) << 6;
        const bool pf = (t + 1 < NT);
        const int abase = aRd + db * 32768;
        const int bbase = bRd + db * 32768;
        s16x8 a[4], b[4];

#pragma unroll
        for (int i = 0; i < 4; ++i) b[i] = *(const s16x8*)(lds + bbase + i * 1024);
#pragma unroll
        for (int i = 0; i < 4; ++i) a[i] = *(const s16x8*)(lds + abase + i * 1024);
        if (pf) issueA(nb, 0, kn);
        BAR();
        __builtin_amdgcn_s_setprio(1);
#pragma unroll
        for (int mi = 0; mi < 4; ++mi)
#pragma unroll
            for (int ni = 0; ni < 4; ++ni)
                acc[mi][ni] = __builtin_amdgcn_mfma_f32_16x16x32_bf16(a[mi], b[ni], acc[mi][ni], 0, 0, 0);
        __builtin_amdgcn_s_setprio(0);
        BAR();

#pragma unroll
        for (int i = 0; i < 4; ++i) a[i] = *(const s16x8*)(lds + abase + (4 + i) * 1024);
        if (pf) issueB(nb, 0, kn);
        BAR();
        __builtin_amdgcn_s_setprio(1);
#pragma unroll
        for (int mi = 0; mi < 4; ++mi)
#pragma unroll
            for (int ni = 0; ni < 4; ++ni)
                acc[4 + mi][ni] = __builtin_amdgcn_mfma_f32_16x16x32_bf16(a[mi], b[ni], acc[4 + mi][ni], 0, 0, 0);
        __builtin_amdgcn_s_setprio(0);
        if (pf) { WAITV4_BAR(); }
        else    { WAITV0_BAR(); }

#pragma unroll
        for (int i = 0; i < 4; ++i) b[i] = *(const s16x8*)(lds + bbase + 8192 + i * 1024);
#pragma unroll
        for (int i = 0; i < 4; ++i) a[i] = *(const s16x8*)(lds + abase + 8192 + i * 1024);
        if (pf) issueA(nb, 1, kn);
        BAR();
        __builtin_amdgcn_s_setprio(1);
#pragma unroll
        for (int mi = 0; mi < 4; ++mi)
#pragma unroll
            for (int ni = 0; ni < 4; ++ni)
                acc[mi][ni] = __builtin_amdgcn_mfma_f32_16x16x32_bf16(a[mi], b[ni], acc[mi][ni], 0, 0, 0);
        __builtin_amdgcn_s_setprio(0);
        BAR();

#pragma unroll
        for (int i = 0; i < 4; ++i) a[i] = *(const s16x8*)(lds + abase + 8192 + (4 + i) * 1024);
        if (pf) issueB(nb, 1, kn);
        BAR();
        __builtin_amdgcn_s_setprio(1);
#pragma unroll
        for (int mi = 0; mi < 4; ++mi)
#pragma unroll
            for (int ni = 0; ni < 4; ++ni)
                acc[4 + mi][ni] = __builtin_amdgcn_mfma_f32_16x16x32_bf16(a[mi], b[ni], acc[4 + mi][ni], 0, 0, 0);
        __builtin_amdgcn_s_setprio(0);
        if (pf) { WAITV4_BAR(); }
    }

    const int rb = (lane >> 4) * 4;
#pragma unroll
    for (int ni = 0; ni < 4; ++ni) {
        const int col = n0 + wc * 64 + ni * 16 + fr;
        const float bv = bias[(long)z * bz + col];
#pragma unroll
        for (int mi = 0; mi < 8; ++mi) {
#pragma unroll
            for (int r = 0; r < 4; ++r) {
                const int row = m0 + wr * 128 + mi * 16 + rb + r;
                float v = acc[mi][ni][r] + bv;
                if (ACT == 1) v = fmaxf(v, 0.f);
                if (ACT == 2) v = v / (1.f + __expf(-v));
                if (OUTF) Cf[(long)z * cfz + (long)row * ldcf + col] = v;
                if (OUTB) Cb[(long)z * cbz + (long)row * ldcb + col] = to_bf16(v);
            }
        }
    }
}

// ================= 128x128 BK=128 8-wave phased GEMM for the N=1024 chain =================
// FIX vs round 6: issueB takes the FULL k offset (weights are indexed by global k);
// only the A-operand uses the segment-masked offset for the virtual concat.
template<int ACT, int SEG, int ADD, int OUTF, int OUTB>
__global__ __launch_bounds__(512, 2) void k_gemm128ph(
    const bf16* __restrict__ A0, const bf16* __restrict__ A1, const bf16* __restrict__ A2,
    const bf16* __restrict__ W, int ldb,
    const float* __restrict__ bias,
    const float* __restrict__ Add,
    float* __restrict__ Cf, int ldcf,
    bf16* __restrict__ Cb, int ldcb,
    int K, int nM)
{
    __shared__ char lds[131072];
    const int tid = threadIdx.x;
    const int wid = tid >> 6, lane = tid & 63;
    const int fid = xcd_swz(blockIdx.x, gridDim.x);
    const int m0 = (fid % nM) * 128;
    const int n0 = (fid / nM) * 128;
    const int wr = wid >> 1, wc = wid & 1;

    // staging: thread t -> row t>>3 (0..63) [+64 for 2nd issue], slot t&7 holds global chunk (t&7)^(row&7)
    const int trow = tid >> 3;
    const int swzc = ((tid & 7) ^ (trow & 7)) * 8;
    const long aoff0 = (long)(m0 + trow) * 1024 + swzc;
    const long aoff1 = aoff0 + (long)64 * 1024;
    const long boff0 = (long)(n0 + trow) * ldb + swzc;
    const long boff1 = boff0 + (long)64 * ldb;

    // reader constants
    const int fr = lane & 15, g = lane >> 4;
    const int ch0 = ((g ^ (fr & 7)) << 4);          // kk parity 0
    const int ch1 = (((4 + g) ^ (fr & 7)) << 4);    // kk parity 1
    const int arow = (wr * 32 + fr) * 128;           // + mi*2048
    const int brow = 65536 + (wc * 64 + fr) * 128;   // + ni*2048

    f32x4 acc[2][4] = {};
    const int NT = K >> 7;

    auto issueA = [&](int db, int kh, const bf16* base, int ko) {
        char* l = lds + db * 32768 + kh * 16384 + wid * 1024;
        gload_lds16(base + aoff0 + ko + kh * 64, l);
        gload_lds16(base + aoff1 + ko + kh * 64, l + 8192);
    };
    auto issueB = [&](int db, int kh, int kfull) {
        char* l = lds + 65536 + db * 32768 + kh * 16384 + wid * 1024;
        gload_lds16(W + boff0 + kfull + kh * 64, l);
        gload_lds16(W + boff1 + kfull + kh * 64, l + 8192);
    };
    auto aseg = [&](int k0, const bf16*& base, int& ko) {
        if (SEG) { int s = k0 >> 10; base = (s == 0 ? A0 : (s == 1 ? A1 : A2)); ko = k0 & 1023; }
        else     { base = A0; ko = k0; }
    };

    { const bf16* b0; int k0o; aseg(0, b0, k0o);
      issueA(0, 0, b0, k0o); issueB(0, 0, 0);
      issueA(0, 1, b0, k0o); issueB(0, 1, 0); }
    WAITV4_BAR();   // kh0 A+B landed; kh1 (4) in flight

    for (int t = 0; t < NT; ++t) {
        const int db = t & 1, nb = db ^ 1;
        const int kn = (t + 1) << 7;
        const bool pf = (t + 1 < NT);
        const bf16* nab = A0; int nko = 0;
        if (pf) aseg(kn, nab, nko);
        const int ab = db * 32768, bb = db * 32768;
        s16x8 a[2], b[4];

        // ---- ph0: kk0 (kh0, p0) ----
#pragma unroll
        for (int i = 0; i < 4; ++i) b[i] = *(const s16x8*)(lds + bb + brow + i * 2048 + ch0);
#pragma unroll
        for (int i = 0; i < 2; ++i) a[i] = *(const s16x8*)(lds + ab + arow + i * 2048 + ch0);
        if (pf) issueA(nb, 0, nab, nko);
        BAR();
        __builtin_amdgcn_s_setprio(1);
#pragma unroll
        for (int mi = 0; mi < 2; ++mi)
#pragma unroll
            for (int ni = 0; ni < 4; ++ni)
                acc[mi][ni] = __builtin_amdgcn_mfma_f32_16x16x32_bf16(a[mi], b[ni], acc[mi][ni], 0, 0, 0);
        __builtin_amdgcn_s_setprio(0);
        BAR();

        // ---- ph1: kk1 (kh0, p1) ----
#pragma unroll
        for (int i = 0; i < 4; ++i) b[i] = *(const s16x8*)(lds + bb + brow + i * 2048 + ch1);
#pragma unroll
        for (int i = 0; i < 2; ++i) a[i] = *(const s16x8*)(lds + ab + arow + i * 2048 + ch1);
        if (pf) issueB(nb, 0, kn);
        BAR();
        __builtin_amdgcn_s_setprio(1);
#pragma unroll
        for (int mi = 0; mi < 2; ++mi)
#pragma unroll
            for (int ni = 0; ni < 4; ++ni)
                acc[mi][ni] = __builtin_amdgcn_mfma_f32_16x16x32_bf16(a[mi], b[ni], acc[mi][ni], 0, 0, 0);
        __builtin_amdgcn_s_setprio(0);
        if (pf) { WAITV4_BAR(); }   // drains t's kh1; t+1's kh0 (4) in flight
        else    { WAITV0_BAR(); }

        // ---- ph2: kk2 (kh1, p0) ----
#pragma unroll
        for (int i = 0; i < 4; ++i) b[i] = *(const s16x8*)(lds + bb + 16384 + brow + i * 2048 + ch0);
#pragma unroll
        for (int i = 0; i < 2; ++i) a[i] = *(const s16x8*)(lds + ab + 16384 + arow + i * 2048 + ch0);
        if (pf) issueA(nb, 1, nab, nko);
        BAR();
        __builtin_amdgcn_s_setprio(1);
#pragma unroll
        for (int mi = 0; mi < 2; ++mi)
#pragma unroll
            for (int ni = 0; ni < 4; ++ni)
                acc[mi][ni] = __builtin_amdgcn_mfma_f32_16x16x32_bf16(a[mi], b[ni], acc[mi][ni], 0, 0, 0);
        __builtin_amdgcn_s_setprio(0);
        BAR();

        // ---- ph3: kk3 (kh1, p1) ----
#pragma unroll
        for (int i = 0; i < 4; ++i) b[i] = *(const s16x8*)(lds + bb + 16384 + brow + i * 2048 + ch1);
#pragma unroll
        for (int i = 0; i < 2; ++i) a[i] = *(const s16x8*)(lds + ab + 16384 + arow + i * 2048 + ch1);
        if (pf) issueB(nb, 1, kn);
        BAR();
        __builtin_amdgcn_s_setprio(1);
#pragma unroll
        for (int mi = 0; mi < 2; ++mi)
#pragma unroll
            for (int ni = 0; ni < 4; ++ni)
                acc[mi][ni] = __builtin_amdgcn_mfma_f32_16x16x32_bf16(a[mi], b[ni], acc[mi][ni], 0, 0, 0);
        __builtin_amdgcn_s_setprio(0);
        if (pf) { WAITV4_BAR(); }   // drains t+1's kh0; kh1 (4) in flight
    }

    const int rb = g * 4;
#pragma unroll
    for (int ni = 0; ni < 4; ++ni) {
        const int col = n0 + wc * 64 + ni * 16 + fr;
        const float bv = bias ? bias[col] : 0.f;
#pragma unroll
        for (int mi = 0; mi < 2; ++mi) {
#pragma unroll
            for (int r = 0; r < 4; ++r) {
                const int row = m0 + wr * 32 + mi * 16 + rb + r;
                float v = acc[mi][ni][r] + bv;
                if (ADD) v += Add[(long)row * 1024 + col];
                if (ACT == 1) v = fmaxf(v, 0.f);
                if (ACT == 2) v = v / (1.f + __expf(-v));
                if (OUTF) Cf[(long)row * ldcf + col] = v;
                if (OUTB) Cb[(long)row * ldcb + col] = to_bf16(v);
            }
        }
    }
}

// ================= 64x128 m97-style GEMM (fallback path only) =================
template<int ACT, int SEG, int ADD>
__global__ __launch_bounds__(256, 4) void k_gemm64(
    const bf16* __restrict__ A0, const bf16* __restrict__ A1, const bf16* __restrict__ A2,
    const bf16* __restrict__ W, int ldb, long wz,
    const float* __restrict__ bias, long bz,
    const float* __restrict__ Add,
    float* __restrict__ Cf, int ldcf,
    bf16* __restrict__ Cb, int ldcb,
    int K, int nM)
{
    __shared__ bf16 As[64 * 32];
    __shared__ bf16 Bs[128 * 32];
    const int tid  = threadIdx.x;
    const int wid  = tid >> 6;
    const int lane = tid & 63;
    const int z = blockIdx.z;

    const int fid = xcd_swz(blockIdx.x, gridDim.x);
    const int m0 = (fid % nM) * 64;
    const int n0 = (fid / nM) * 128;

    const int srow = tid >> 2;
    const int scol = (tid & 3) * 8;
    const long arow = (long)(m0 + srow) * 1024 + scol;
    const bf16* a0 = A0 + arow;
    const bf16* a1 = SEG ? (A1 + arow) : nullptr;
    const bf16* a2 = SEG ? (A2 + arow) : nullptr;
    const bf16* bg = W + (long)z * wz + (long)(n0 + srow) * ldb + scol;

    char* asb = (char*)As;
    char* bsb = (char*)Bs;

    f32x4 acc[2][4] = {};

    const int wm = (wid >> 1) * 32;
    const int wn = (wid & 1) * 64;
    const int fr = lane & 15;
    const int kq = (lane >> 4) * 8;

    for (int k0 = 0; k0 < K; k0 += 32) {
        const bf16* ap;
        if (SEG) {
            const int seg = k0 >> 10, ko = k0 & 1023;
            ap = (seg == 0 ? a0 : (seg == 1 ? a1 : a2)) + ko;
        } else {
            ap = a0 + k0;
        }
        const bf16* bp = bg + k0;

        __syncthreads();
        gload_lds16(ap,                   asb + wid * 1024);
        gload_lds16(bp,                   bsb + wid * 1024);
        gload_lds16(bp + (long)64 * ldb,  bsb + 4096 + wid * 1024);
        __syncthreads();

        s16x8 af[2], bfv[4];
#pragma unroll
        for (int i = 0; i < 2; ++i)
            af[i] = *(const s16x8*)(As + (wm + i * 16 + fr) * 32 + kq);
#pragma unroll
        for (int i = 0; i < 4; ++i)
            bfv[i] = *(const s16x8*)(Bs + (wn + i * 16 + fr) * 32 + kq);
#pragma unroll
        for (int mi = 0; mi < 2; ++mi)
#pragma unroll
            for (int ni = 0; ni < 4; ++ni)
                acc[mi][ni] = __builtin_amdgcn_mfma_f32_16x16x32_bf16(
                    af[mi], bfv[ni], acc[mi][ni], 0, 0, 0);
    }

    const int rb = (lane >> 4) * 4;
#pragma unroll
    for (int ni = 0; ni < 4; ++ni) {
        const int col = n0 + wn + ni * 16 + fr;
        const float bv = bias ? bias[(long)z * bz + col] : 0.f;
#pragma unroll
        for (int mi = 0; mi < 2; ++mi) {
#pragma unroll
            for (int r = 0; r < 4; ++r) {
                const int row = m0 + wm + mi * 16 + rb + r;
                float v = acc[mi][ni][r] + bv;
                if (ADD) v += Add[(long)row * 1024 + col];
                if (ACT == 1) v = fmaxf(v, 0.f);
                if (ACT == 2) v = v / (1.f + __expf(-v));
                if (Cf) Cf[(long)row * ldcf + col] = v;
                if (Cb) Cb[(long)row * ldcb + col] = to_bf16(v);
            }
        }
    }
}

// ---------------- fused mask head ----------------
__global__ __launch_bounds__(64) void k_mask_softmax(
    const bf16* __restrict__ t, const float* __restrict__ W2,
    const float* __restrict__ b2, float* __restrict__ mask_out)
{
    const int tok = blockIdx.x;
    const int lane = threadIdx.x;
    float part[16];
#pragma unroll
    for (int e = 0; e < 16; ++e) part[e] = 0.f;
    const bf16* tr = t + (long)tok * 1024 + lane * 16;
#pragma unroll
    for (int kk = 0; kk < 16; ++kk) {
        float x = __bfloat162float(tr[kk]);
        const float* wr = W2 + (long)(lane * 16 + kk) * 16;
#pragma unroll
        for (int e = 0; e < 16; ++e) part[e] += x * wr[e];
    }
#pragma unroll
    for (int e = 0; e < 16; ++e) {
#pragma unroll
        for (int off = 32; off >= 1; off >>= 1)
            part[e] += __shfl_down(part[e], off);
    }
    if (lane == 0) {
        float vals[16], mx = -1e30f;
#pragma unroll
        for (int e = 0; e < 16; ++e) { vals[e] = part[e] + b2[e]; mx = fmaxf(mx, vals[e]); }
        float s = 0.f;
#pragma unroll
        for (int e = 0; e < 16; ++e) { vals[e] = __expf(vals[e] - mx); s += vals[e]; }
        float inv = 1.f / s;
#pragma unroll
        for (int e = 0; e < 16; ++e) mask_out[tok * 16 + e] = vals[e] * inv;
    }
}

// ---------------- qk = sum_e mask[tok][e] * EO[tok][e][:] -> bf16 ----------------
__global__ void k_qk(const float* __restrict__ EO, const float* __restrict__ mask,
                     bf16* __restrict__ qkb)
{
    int i = blockIdx.x * blockDim.x + threadIdx.x;
    int tok = i >> 8;
    int d4  = (i & 255) << 2;
    const float* eo = EO + (long)tok * 16384 + d4;
    const float* mk = mask + tok * 16;
    float4 s = make_float4(0.f, 0.f, 0.f, 0.f);
#pragma unroll
    for (int e = 0; e < 16; ++e) {
        float m = mk[e];
        float4 v = *(const float4*)(eo + e * 1024);
        s.x += m * v.x; s.y += m * v.y; s.z += m * v.z; s.w += m * v.w;
    }
    bf16x4_pack o{to_bf16(s.x), to_bf16(s.y), to_bf16(s.z), to_bf16(s.w)};
    ((bf16x4_pack*)qkb)[i] = o;
}

extern "C" void kernel_launch(void* const* d_in, const int* in_sizes, int n_in,
                              void* d_out, int out_size, void* d_ws, size_t ws_size,
                              hipStream_t stream)
{
    const int Mtok = 4096, D = 1024, E = 16, V = 32000, DIN = 3072;

    const float* L      = (const float*)d_in[0];
    const float* mL     = (const float*)d_in[1];
    const float* prompt = (const float*)d_in[2];
    const float* noise  = (const float*)d_in[3];
    const float* qa_W1 = (const float*)d_in[4];  const float* qa_b1 = (const float*)d_in[5];
    const float* qa_W2 = (const float*)d_in[6];  const float* qa_b2 = (const float*)d_in[7];
    const float* qb_W1 = (const float*)d_in[8];  const float* qb_b1 = (const float*)d_in[9];
    const float* qb_W2 = (const float*)d_in[10]; const float* qb_b2 = (const float*)d_in[11];
    const float* qc_W1 = (const float*)d_in[12]; const float* qc_b1 = (const float*)d_in[13];
    const float* qc_W2 = (const float*)d_in[14]; const float* qc_b2 = (const float*)d_in[15];
    const float* ek_W1 = (const float*)d_in[16]; const float* ek_b1 = (const float*)d_in[17];
    const float* ek_W2 = (const float*)d_in[18]; const float* ek_b2 = (const float*)d_in[19];
    const float* md_W1 = (const float*)d_in[20]; const float* md_b1 = (const float*)d_in[21];
    const float* md_W2 = (const float*)d_in[22]; const float* md_b2 = (const float*)d_in[23];
    const float* td_W  = (const float*)d_in[24]; const float* td_b  = (const float*)d_in[25];

    float* out = (float*)d_out;
    float* out_L2   = out;
    float* out_mLp  = out + 4194304;
    float* out_mask = out + 8388608;
    float* out_txt  = out + 8454144;
    float* out_EO   = out + 139526144;

    char* ws = (char*)d_ws;
    size_t off = 0;
    auto alloc = [&](size_t bytes) -> void* {
        void* p = ws + off;
        off += (bytes + 255) & ~(size_t)255;
        return p;
    };

    bf16* wqa1 = (bf16*)alloc((size_t)DIN * D * 2);
    bf16* wqa2 = (bf16*)alloc((size_t)D * D * 2);
    bf16* wqb1 = (bf16*)alloc((size_t)DIN * D * 2);
    bf16* wqb2 = (bf16*)alloc((size_t)D * D * 2);
    bf16* wqc1 = (bf16*)alloc((size_t)DIN * D * 2);
    bf16* wqc2 = (bf16*)alloc((size_t)D * D * 2);
    bf16* wmd1 = (bf16*)alloc((size_t)D * D * 2);
    bf16* wek1 = (bf16*)alloc((size_t)E * D * D * 2);
    bf16* wek2 = (bf16*)alloc((size_t)E * D * D * 2);
    bf16* wtd  = (bf16*)alloc((size_t)D * V * 2);

    bf16* Lb   = (bf16*)alloc((size_t)Mtok * D * 2);
    bf16* mLb  = (bf16*)alloc((size_t)Mtok * D * 2);
    bf16* Pb   = (bf16*)alloc((size_t)Mtok * D * 2);
    bf16* Nb   = (bf16*)alloc((size_t)Mtok * D * 2);
    bf16* hbuf = (bf16*)alloc((size_t)Mtok * D * 2);
    bf16* L1b  = (bf16*)alloc((size_t)Mtok * D * 2);
    bf16* sLb  = (bf16*)alloc((size_t)Mtok * D * 2);
    bf16* tb   = (bf16*)alloc((size_t)Mtok * D * 2);
    bf16* qkb  = (bf16*)alloc((size_t)Mtok * D * 2);
    bf16* L2b  = (bf16*)alloc((size_t)Mtok * D * 2);
    float* paf = (float*)alloc((size_t)Mtok * D * 4);   // qa shared partial (fp32)

    const size_t hall_bytes = (size_t)E * Mtok * D * 2;
    bool batched = (off + hall_bytes + 256 <= ws_size);
    bf16* hall = batched ? (bf16*)alloc(hall_bytes) : nullptr;

    auto conv = [&](const float* src, bf16* dst, long n) {
        int n4 = (int)(n / 4);
        k_conv_f32_bf16<<<dim3((n4 + 255) / 256), dim3(256), 0, stream>>>(src, dst, n4);
    };
    conv(L, Lb, (long)Mtok * D);
    conv(mL, mLb, (long)Mtok * D);
    conv(prompt, Pb, (long)Mtok * D);
    conv(noise, Nb, (long)Mtok * D);

    auto transp = [&](const float* src, bf16* dst, int K, int N, int Z, long inz, long outz) {
        dim3 g(N / 32, K / 32, Z);
        k_transpose_f32_bf16<<<g, dim3(256), 0, stream>>>(src, dst, K, N, inz, outz);
    };
    transp(qa_W1, wqa1, DIN, D, 1, 0, 0);
    transp(qa_W2, wqa2, D, D, 1, 0, 0);
    transp(qb_W1, wqb1, DIN, D, 1, 0, 0);
    transp(qb_W2, wqb2, D, D, 1, 0, 0);
    transp(qc_W1, wqc1, DIN, D, 1, 0, 0);
    transp(qc_W2, wqc2, D, D, 1, 0, 0);
    transp(md_W1, wmd1, D, D, 1, 0, 0);
    transp(ek_W1, wek1, D, D, 16, (long)D * D, (long)D * D);
    transp(ek_W2, wek2, D, D, 16, (long)D * D, (long)D * D);
    transp(td_W,  wtd,  D, V, 1, 0, 0);

    const int nM128 = Mtok / 128;               // 32
    dim3 gph(nM128 * (D / 128), 1, 1);          // 256 WGs
    dim3 bph(512);

    // pa = prompt @ qaW1b + mL @ qaW1c   (K=2048, fp32 out, no bias/act)
    k_gemm128ph<0, 1, 0, 1, 0><<<gph, bph, 0, stream>>>(
        Pb, mLb, mLb, wqa1 + 1024, DIN, nullptr, nullptr,
        paf, D, nullptr, 0, 2048, nM128);

    // L1 = qa([L | prompt | mL]) : h = relu(L@W1a + pa + b1); L1 = h@W2 + b2
    k_gemm128ph<1, 0, 1, 0, 1><<<gph, bph, 0, stream>>>(
        Lb, Lb, Lb, wqa1, DIN, qa_b1, paf,
        nullptr, 0, hbuf, D, 1024, nM128);
    k_gemm128ph<0, 0, 0, 0, 1><<<gph, bph, 0, stream>>>(
        hbuf, hbuf, hbuf, wqa2, D, qa_b2, nullptr,
        nullptr, 0, L1b, D, 1024, nM128);

    // sL = qb([noise | prompt | L1])
    k_gemm128ph<1, 1, 0, 0, 1><<<gph, bph, 0, stream>>>(
        Nb, Pb, L1b, wqb1, DIN, qb_b1, nullptr,
        nullptr, 0, hbuf, D, 3072, nM128);
    k_gemm128ph<0, 0, 0, 0, 1><<<gph, bph, 0, stream>>>(
        hbuf, hbuf, hbuf, wqb2, D, qb_b2, nullptr,
        nullptr, 0, sLb, D, 1024, nM128);

    // mask = softmax(relu(sL @ md_W1 + b1) @ md_W2 + b2)
    k_gemm128ph<1, 0, 0, 0, 1><<<gph, bph, 0, stream>>>(
        sLb, sLb, sLb, wmd1, D, md_b1, nullptr,
        nullptr, 0, tb, D, 1024, nM128);
    k_mask_softmax<<<dim3(Mtok), dim3(64), 0, stream>>>(tb, md_W2, md_b2, out_mask);

    // experts via 256^2 phased kernel (z=16)
    if (batched) {
        dim3 ge(16 * 4, 1, 16), be(512);
        k_gemm256<2, 0, 1><<<ge, be, 0, stream>>>(
            L1b, D, 0, wek1, (long)D * D, ek_b1, D,
            nullptr, 0, 0, hall, D, (long)Mtok * D, D, 4);
        k_gemm256<0, 1, 0><<<ge, be, 0, stream>>>(
            hall, D, (long)Mtok * D, wek2, (long)D * D, ek_b2, D,
            out_EO, E * D, D, nullptr, 0, 0, D, 4);
    } else {
        dim3 b64(256);
        const int nM64 = Mtok / 64;
        dim3 g64(nM64 * (D / 128), 1, 1);
        for (int e = 0; e < 16; ++e) {
            k_gemm64<2, 0, 0><<<g64, b64, 0, stream>>>(
                L1b, L1b, L1b, wek1 + (size_t)e * D * D, D, 0, ek_b1 + e * D, 0, nullptr,
                nullptr, 0, hbuf, D, 1024, nM64);
            k_gemm64<0, 0, 0><<<g64, b64, 0, stream>>>(
                hbuf, hbuf, hbuf, wek2 + (size_t)e * D * D, D, 0, ek_b2 + e * D, 0, nullptr,
                out_EO + e * D, E * D, nullptr, 0, 1024, nM64);
        }
    }

    // qk = sum_e mask * EO
    k_qk<<<dim3(4096), dim3(256), 0, stream>>>(out_EO, out_mask, qkb);

    // L2 = qa([qk | prompt | mL]) : h = relu(qk@W1a + pa + b1); L2 = h@W2 + b2
    k_gemm128ph<1, 0, 1, 0, 1><<<gph, bph, 0, stream>>>(
        qkb, qkb, qkb, wqa1, DIN, qa_b1, paf,
        nullptr, 0, hbuf, D, 1024, nM128);
    k_gemm128ph<0, 0, 0, 1, 1><<<gph, bph, 0, stream>>>(
        hbuf, hbuf, hbuf, wqa2, D, qa_b2, nullptr,
        out_L2, D, L2b, D, 1024, nM128);

    // mL_pred = qc([mL | prompt | L2])
    k_gemm128ph<1, 1, 0, 0, 1><<<gph, bph, 0, stream>>>(
        mLb, Pb, L2b, wqc1, DIN, qc_b1, nullptr,
        nullptr, 0, hbuf, D, 3072, nM128);
    k_gemm128ph<0, 0, 0, 1, 0><<<gph, bph, 0, stream>>>(
        hbuf, hbuf, hbuf, wqc2, D, qc_b2, nullptr,
        out_mLp, D, nullptr, 0, 1024, nM128);

    // text_logits = L2 @ td_W + td_b  (256^2 phased)
    {
        dim3 gl(16 * 125, 1, 1), bl(512);
        k_gemm256<0, 1, 0><<<gl, bl, 0, stream>>>(
            L2b, D, 0, wtd, 0, td_b, 0,
            out_txt, V, 0, nullptr, 0, 0, D, 125);
    }
}

// Round 8
// 1168.791 us; speedup vs baseline: 1.4123x; 1.0235x over previous
//
#include <hip/hip_runtime.h>
#include <hip/hip_bf16.h>
#include <cstdint>
#include <cstddef>

using bf16 = __hip_bfloat16;

typedef __attribute__((ext_vector_type(4))) float f32x4;
typedef __attribute__((ext_vector_type(8))) short s16x8;

__device__ __forceinline__ bf16 to_bf16(float v) { return __float2bfloat16(v); }

struct alignas(8) bf16x4_pack { bf16 x, y, z, w; };

// bijective XCD-chunking swizzle (m204)
__device__ __forceinline__ int xcd_swz(int orig, int nwg) {
    int xcd = orig & 7, base = orig >> 3;
    int q = nwg >> 3, r = nwg & 7;
    return (xcd < r ? xcd * (q + 1) : r * (q + 1) + (xcd - r) * q) + base;
}

#define BAR()        asm volatile("s_barrier" ::: "memory")
#define WAITV4_BAR() asm volatile("s_waitcnt vmcnt(4)\ns_barrier" ::: "memory")
#define WAITV0_BAR() asm volatile("s_waitcnt vmcnt(0)\ns_barrier" ::: "memory")

// ---------------- fused fp32 -> bf16 conversion of the 4 activation inputs ----------------
__global__ void k_conv4(const float* __restrict__ a, const float* __restrict__ b,
                        const float* __restrict__ c, const float* __restrict__ d,
                        bf16* __restrict__ oa, bf16* __restrict__ ob,
                        bf16* __restrict__ oc, bf16* __restrict__ od)
{
    int i = blockIdx.x * blockDim.x + threadIdx.x;      // 4 * 1048576 units of 4 floats
    int sel = i >> 20, li = i & 1048575;
    const float* src = sel == 0 ? a : (sel == 1 ? b : (sel == 2 ? c : d));
    bf16* dst = sel == 0 ? oa : (sel == 1 ? ob : (sel == 2 ? oc : od));
    float4 v = ((const float4*)src)[li];
    bf16x4_pack o{to_bf16(v.x), to_bf16(v.y), to_bf16(v.z), to_bf16(v.w)};
    ((bf16x4_pack*)dst)[li] = o;
}

// ---------------- fp32 [K][N] -> bf16 [N][K] tiled transpose (single job) ----------------
__global__ __launch_bounds__(256) void k_transpose_f32_bf16(
    const float* __restrict__ in, bf16* __restrict__ out, int K, int N)
{
    __shared__ float t[32][33];
    int n0 = blockIdx.x * 32, k0 = blockIdx.y * 32;
    int tx = threadIdx.x & 31, ty = threadIdx.x >> 5;
#pragma unroll
    for (int r = 0; r < 32; r += 8)
        t[ty + r][tx] = in[(long)(k0 + ty + r) * N + (n0 + tx)];
    __syncthreads();
#pragma unroll
    for (int r = 0; r < 32; r += 8)
        out[(long)(n0 + ty + r) * K + (k0 + tx)] = to_bf16(t[tx][ty + r]);
}

// ---------------- multi-job transposes: 36 x (1024x1024) jobs, z-indexed ----------------
__global__ __launch_bounds__(256) void k_transpose_1k(
    const float* __restrict__ s0, const float* __restrict__ s1,
    const float* __restrict__ s2, const float* __restrict__ s3,
    const float* __restrict__ ek1, const float* __restrict__ ek2,
    bf16* __restrict__ d0, bf16* __restrict__ d1,
    bf16* __restrict__ d2, bf16* __restrict__ d3,
    bf16* __restrict__ dk1, bf16* __restrict__ dk2)
{
    __shared__ float t[32][33];
    const int z = blockIdx.z;
    const float* in; bf16* out;
    if (z < 4) {
        in  = z == 0 ? s0 : (z == 1 ? s1 : (z == 2 ? s2 : s3));
        out = z == 0 ? d0 : (z == 1 ? d1 : (z == 2 ? d2 : d3));
    } else if (z < 20) {
        in = ek1 + (long)(z - 4) * 1048576;  out = dk1 + (long)(z - 4) * 1048576;
    } else {
        in = ek2 + (long)(z - 20) * 1048576; out = dk2 + (long)(z - 20) * 1048576;
    }
    int n0 = blockIdx.x * 32, k0 = blockIdx.y * 32;
    int tx = threadIdx.x & 31, ty = threadIdx.x >> 5;
#pragma unroll
    for (int r = 0; r < 32; r += 8)
        t[ty + r][tx] = in[(long)(k0 + ty + r) * 1024 + (n0 + tx)];
    __syncthreads();
#pragma unroll
    for (int r = 0; r < 32; r += 8)
        out[(long)(n0 + ty + r) * 1024 + (k0 + tx)] = to_bf16(t[tx][ty + r]);
}

// ---------------- multi-job transposes: 3 x (3072x1024) jobs ----------------
__global__ __launch_bounds__(256) void k_transpose_3k(
    const float* __restrict__ s0, const float* __restrict__ s1, const float* __restrict__ s2,
    bf16* __restrict__ d0, bf16* __restrict__ d1, bf16* __restrict__ d2)
{
    __shared__ float t[32][33];
    const int z = blockIdx.z;
    const float* in = z == 0 ? s0 : (z == 1 ? s1 : s2);
    bf16* out = z == 0 ? d0 : (z == 1 ? d1 : d2);
    int n0 = blockIdx.x * 32, k0 = blockIdx.y * 32;
    int tx = threadIdx.x & 31, ty = threadIdx.x >> 5;
#pragma unroll
    for (int r = 0; r < 32; r += 8)
        t[ty + r][tx] = in[(long)(k0 + ty + r) * 1024 + (n0 + tx)];
    __syncthreads();
#pragma unroll
    for (int r = 0; r < 32; r += 8)
        out[(long)(n0 + ty + r) * 3072 + (k0 + tx)] = to_bf16(t[tx][ty + r]);
}

// ---------------- async global->LDS 16B helper ----------------
__device__ __forceinline__ void gload_lds16(const void* g, void* l) {
    __builtin_amdgcn_global_load_lds(
        (const __attribute__((address_space(1))) void*)g,
        (__attribute__((address_space(3))) void*)l,
        16, 0, 0);
}

// ================= 256x256 BK=64 8-wave phased GEMM (round-3/5/7 proven) =================
template<int ACT, int OUTF, int OUTB>   // ACT: 0 none, 1 relu, 2 silu
__global__ __launch_bounds__(512, 2) void k_gemm256(
    const bf16* __restrict__ A, int lda, long az,
    const bf16* __restrict__ W, long wz,
    const float* __restrict__ bias, long bz,
    float* __restrict__ Cf, int ldcf, long cfz,
    bf16* __restrict__ Cb, int ldcb, long cbz,
    int K, int nN)
{
    __shared__ char lds[131072];
    const int tid = threadIdx.x;
    const int wid = tid >> 6, lane = tid & 63;
    const int z = blockIdx.z;
    const int fid = xcd_swz(blockIdx.x, gridDim.x);
    const int m0 = (fid / nN) * 256;
    const int n0 = (fid % nN) * 256;
    const int wr = wid >> 2, wc = wid & 3;

    const int srow = tid >> 2;
    const int sk   = ((tid & 3) ^ (srow & 3)) * 8;
    const bf16* Ag = A + (long)z * az + (long)(m0 + srow) * lda + sk;
    const bf16* Wg = W + (long)z * wz + (long)(n0 + srow) * K + sk;

    const int fr = lane & 15;
    const int xorv = (((lane >> 4) ^ (lane & 3)) << 4);
    const int aRd = wr * 16384 + fr * 64 + xorv;
    const int bRd = 65536 + (wc >> 1) * 16384 + ((wc & 1) << 12) + fr * 64 + xorv;

    f32x4 acc[8][4] = {};
    const int NT = K >> 6;

    auto issueA = [&](int db, int kh, int kb) {
        char* l = lds + db * 32768 + kh * 8192 + wid * 1024;
        gload_lds16(Ag + kb + kh * 32, l);
        gload_lds16(Ag + kb + kh * 32 + (long)128 * lda, l + 16384);
    };
    auto issueB = [&](int db, int kh, int kb) {
        char* l = lds + 65536 + db * 32768 + kh * 8192 + wid * 1024;
        gload_lds16(Wg + kb + kh * 32, l);
        gload_lds16(Wg + kb + kh * 32 + (long)128 * K, l + 16384);
    };

    issueA(0, 0, 0); issueB(0, 0, 0);
    issueA(0, 1, 0); issueB(0, 1, 0);
    WAITV4_BAR();

    for (int t = 0; t < NT; ++t) {
        const int db = t & 1, nb = db ^ 1;
        const int kn = (t + 1) << 6;
        const bool pf = (t + 1 < NT);
        const int abase = aRd + db * 32768;
        const int bbase = bRd + db * 32768;
        s16x8 a[4], b[4];

#pragma unroll
        for (int i = 0; i < 4; ++i) b[i] = *(const s16x8*)(lds + bbase + i * 1024);
#pragma unroll
        for (int i = 0; i < 4; ++i) a[i] = *(const s16x8*)(lds + abase + i * 1024);
        if (pf) issueA(nb, 0, kn);
        BAR();
        __builtin_amdgcn_s_setprio(1);
#pragma unroll
        for (int mi = 0; mi < 4; ++mi)
#pragma unroll
            for (int ni = 0; ni < 4; ++ni)
                acc[mi][ni] = __builtin_amdgcn_mfma_f32_16x16x32_bf16(a[mi], b[ni], acc[mi][ni], 0, 0, 0);
        __builtin_amdgcn_s_setprio(0);
        BAR();

#pragma unroll
        for (int i = 0; i < 4; ++i) a[i] = *(const s16x8*)(lds + abase + (4 + i) * 1024);
        if (pf) issueB(nb, 0, kn);
        BAR();
        __builtin_amdgcn_s_setprio(1);
#pragma unroll
        for (int mi = 0; mi < 4; ++mi)
#pragma unroll
            for (int ni = 0; ni < 4; ++ni)
                acc[4 + mi][ni] = __builtin_amdgcn_mfma_f32_16x16x32_bf16(a[mi], b[ni], acc[4 + mi][ni], 0, 0, 0);
        __builtin_amdgcn_s_setprio(0);
        if (pf) { WAITV4_BAR(); }
        else    { WAITV0_BAR(); }

#pragma unroll
        for (int i = 0; i < 4; ++i) b[i] = *(const s16x8*)(lds + bbase + 8192 + i * 1024);
#pragma unroll
        for (int i = 0; i < 4; ++i) a[i] = *(const s16x8*)(lds + abase + 8192 + i * 1024);
        if (pf) issueA(nb, 1, kn);
        BAR();
        __builtin_amdgcn_s_setprio(1);
#pragma unroll
        for (int mi = 0; mi < 4; ++mi)
#pragma unroll
            for (int ni = 0; ni < 4; ++ni)
                acc[mi][ni] = __builtin_amdgcn_mfma_f32_16x16x32_bf16(a[mi], b[ni], acc[mi][ni], 0, 0, 0);
        __builtin_amdgcn_s_setprio(0);
        BAR();

#pragma unroll
        for (int i = 0; i < 4; ++i) a[i] = *(const s16x8*)(lds + abase + 8192 + (4 + i) * 1024);
        if (pf) issueB(nb, 1, kn);
        BAR();
        __builtin_amdgcn_s_setprio(1);
#pragma unroll
        for (int mi = 0; mi < 4; ++mi)
#pragma unroll
            for (int ni = 0; ni < 4; ++ni)
                acc[4 + mi][ni] = __builtin_amdgcn_mfma_f32_16x16x32_bf16(a[mi], b[ni], acc[4 + mi][ni], 0, 0, 0);
        __builtin_amdgcn_s_setprio(0);
        if (pf) { WAITV4_BAR(); }
    }

    const int rb = (lane >> 4) * 4;
#pragma unroll
    for (int ni = 0; ni < 4; ++ni) {
        const int col = n0 + wc * 64 + ni * 16 + fr;
        const float bv = bias[(long)z * bz + col];
#pragma unroll
        for (int mi = 0; mi < 8; ++mi) {
#pragma unroll
            for (int r = 0; r < 4; ++r) {
                const int row = m0 + wr * 128 + mi * 16 + rb + r;
                float v = acc[mi][ni][r] + bv;
                if (ACT == 1) v = fmaxf(v, 0.f);
                if (ACT == 2) v = v / (1.f + __expf(-v));
                if (OUTF) Cf[(long)z * cfz + (long)row * ldcf + col] = v;
                if (OUTB) Cb[(long)z * cbz + (long)row * ldcb + col] = to_bf16(v);
            }
        }
    }
}

// ================= 128x128 BK=128 8-wave phased GEMM, 2 merged phases/K-tile =================
// vs round 7: ph0+ph1 merged (both read kh0 slab), ph2+ph3 merged -> 16 MFMA between
// barriers, half the barrier count. Ledger: prologue 8 loads, WAITV4 (kh0 in);
// per phase issue A+B of one kh (4 loads, outstanding 8), end-phase WAITV4 drains the
// slab needed by the NEXT phase (1-phase slack; chain A/W are L2/L3-resident).
template<int ACT, int SEG, int ADD, int OUTF, int OUTB>
__global__ __launch_bounds__(512, 2) void k_gemm128ph(
    const bf16* __restrict__ A0, const bf16* __restrict__ A1, const bf16* __restrict__ A2,
    const bf16* __restrict__ W, int ldb,
    const float* __restrict__ bias,
    const float* __restrict__ Add,
    float* __restrict__ Cf, int ldcf,
    bf16* __restrict__ Cb, int ldcb,
    int K, int nM)
{
    __shared__ char lds[131072];
    const int tid = threadIdx.x;
    const int wid = tid >> 6, lane = tid & 63;
    const int fid = xcd_swz(blockIdx.x, gridDim.x);
    const int m0 = (fid % nM) * 128;
    const int n0 = (fid / nM) * 128;
    const int wr = wid >> 1, wc = wid & 1;

    const int trow = tid >> 3;
    const int swzc = ((tid & 7) ^ (trow & 7)) * 8;
    const long aoff0 = (long)(m0 + trow) * 1024 + swzc;
    const long aoff1 = aoff0 + (long)64 * 1024;
    const long boff0 = (long)(n0 + trow) * ldb + swzc;
    const long boff1 = boff0 + (long)64 * ldb;

    const int fr = lane & 15, g = lane >> 4;
    const int ch0 = ((g ^ (fr & 7)) << 4);          // kk parity 0
    const int ch1 = (((4 + g) ^ (fr & 7)) << 4);    // kk parity 1
    const int arow = (wr * 32 + fr) * 128;           // + mi*2048
    const int brow = 65536 + (wc * 64 + fr) * 128;   // + ni*2048

    f32x4 acc[2][4] = {};
    const int NT = K >> 7;

    auto issueA = [&](int db, int kh, const bf16* base, int ko) {
        char* l = lds + db * 32768 + kh * 16384 + wid * 1024;
        gload_lds16(base + aoff0 + ko + kh * 64, l);
        gload_lds16(base + aoff1 + ko + kh * 64, l + 8192);
    };
    auto issueB = [&](int db, int kh, int kfull) {
        char* l = lds + 65536 + db * 32768 + kh * 16384 + wid * 1024;
        gload_lds16(W + boff0 + kfull + kh * 64, l);
        gload_lds16(W + boff1 + kfull + kh * 64, l + 8192);
    };
    auto aseg = [&](int k0, const bf16*& base, int& ko) {
        if (SEG) { int s = k0 >> 10; base = (s == 0 ? A0 : (s == 1 ? A1 : A2)); ko = k0 & 1023; }
        else     { base = A0; ko = k0; }
    };

    { const bf16* b0; int k0o; aseg(0, b0, k0o);
      issueA(0, 0, b0, k0o); issueB(0, 0, 0);
      issueA(0, 1, b0, k0o); issueB(0, 1, 0); }
    WAITV4_BAR();   // kh0 A+B landed; kh1 (4) in flight

    for (int t = 0; t < NT; ++t) {
        const int db = t & 1, nb = db ^ 1;
        const int kn = (t + 1) << 7;
        const bool pf = (t + 1 < NT);
        const bf16* nab = A0; int nko = 0;
        if (pf) aseg(kn, nab, nko);
        const int ab = db * 32768, bb = db * 32768;
        s16x8 a0[2], a1[2], b0[4], b1[4];

        // ---- merged phase 0: kh0 slab (kk0 + kk1) ----
#pragma unroll
        for (int i = 0; i < 4; ++i) b0[i] = *(const s16x8*)(lds + bb + brow + i * 2048 + ch0);
#pragma unroll
        for (int i = 0; i < 4; ++i) b1[i] = *(const s16x8*)(lds + bb + brow + i * 2048 + ch1);
#pragma unroll
        for (int i = 0; i < 2; ++i) a0[i] = *(const s16x8*)(lds + ab + arow + i * 2048 + ch0);
#pragma unroll
        for (int i = 0; i < 2; ++i) a1[i] = *(const s16x8*)(lds + ab + arow + i * 2048 + ch1);
        if (pf) { issueA(nb, 0, nab, nko); issueB(nb, 0, kn); }
        BAR();
        __builtin_amdgcn_s_setprio(1);
#pragma unroll
        for (int mi = 0; mi < 2; ++mi)
#pragma unroll
            for (int ni = 0; ni < 4; ++ni)
                acc[mi][ni] = __builtin_amdgcn_mfma_f32_16x16x32_bf16(a0[mi], b0[ni], acc[mi][ni], 0, 0, 0);
#pragma unroll
        for (int mi = 0; mi < 2; ++mi)
#pragma unroll
            for (int ni = 0; ni < 4; ++ni)
                acc[mi][ni] = __builtin_amdgcn_mfma_f32_16x16x32_bf16(a1[mi], b1[ni], acc[mi][ni], 0, 0, 0);
        __builtin_amdgcn_s_setprio(0);
        if (pf) { WAITV4_BAR(); }   // drains t's kh1 (issued last tile); t+1 kh0 (4) in flight
        else    { WAITV0_BAR(); }

        // ---- merged phase 1: kh1 slab (kk2 + kk3) ----
#pragma unroll
        for (int i = 0; i < 4; ++i) b0[i] = *(const s16x8*)(lds + bb + 16384 + brow + i * 2048 + ch0);
#pragma unroll
        for (int i = 0; i < 4; ++i) b1[i] = *(const s16x8*)(lds + bb + 16384 + brow + i * 2048 + ch1);
#pragma unroll
        for (int i = 0; i < 2; ++i) a0[i] = *(const s16x8*)(lds + ab + 16384 + arow + i * 2048 + ch0);
#pragma unroll
        for (int i = 0; i < 2; ++i) a1[i] = *(const s16x8*)(lds + ab + 16384 + arow + i * 2048 + ch1);
        if (pf) { issueA(nb, 1, nab, nko); issueB(nb, 1, kn); }
        BAR();
        __builtin_amdgcn_s_setprio(1);
#pragma unroll
        for (int mi = 0; mi < 2; ++mi)
#pragma unroll
            for (int ni = 0; ni < 4; ++ni)
                acc[mi][ni] = __builtin_amdgcn_mfma_f32_16x16x32_bf16(a0[mi], b0[ni], acc[mi][ni], 0, 0, 0);
#pragma unroll
        for (int mi = 0; mi < 2; ++mi)
#pragma unroll
            for (int ni = 0; ni < 4; ++ni)
                acc[mi][ni] = __builtin_amdgcn_mfma_f32_16x16x32_bf16(a1[mi], b1[ni], acc[mi][ni], 0, 0, 0);
        __builtin_amdgcn_s_setprio(0);
        if (pf) { WAITV4_BAR(); }   // drains t+1's kh0; kh1 (4) in flight
    }

    const int rb = g * 4;
#pragma unroll
    for (int ni = 0; ni < 4; ++ni) {
        const int col = n0 + wc * 64 + ni * 16 + fr;
        const float bv = bias ? bias[col] : 0.f;
#pragma unroll
        for (int mi = 0; mi < 2; ++mi) {
#pragma unroll
            for (int r = 0; r < 4; ++r) {
                const int row = m0 + wr * 32 + mi * 16 + rb + r;
                float v = acc[mi][ni][r] + bv;
                if (ADD) v += Add[(long)row * 1024 + col];
                if (ACT == 1) v = fmaxf(v, 0.f);
                if (ACT == 2) v = v / (1.f + __expf(-v));
                if (OUTF) Cf[(long)row * ldcf + col] = v;
                if (OUTB) Cb[(long)row * ldcb + col] = to_bf16(v);
            }
        }
    }
}

// ================= 64x128 m97-style GEMM (fallback path only) =================
template<int ACT, int SEG, int ADD>
__global__ __launch_bounds__(256, 4) void k_gemm64(
    const bf16* __restrict__ A0, const bf16* __restrict__ A1, const bf16* __restrict__ A2,
    const bf16* __restrict__ W, int ldb, long wz,
    const float* __restrict__ bias, long bz,
    const float* __restrict__ Add,
    float* __restrict__ Cf, int ldcf,
    bf16* __restrict__ Cb, int ldcb,
    int K, int nM)
{
    __shared__ bf16 As[64 * 32];
    __shared__ bf16 Bs[128 * 32];
    const int tid  = threadIdx.x;
    const int wid  = tid >> 6;
    const int lane = tid & 63;
    const int z = blockIdx.z;

    const int fid = xcd_swz(blockIdx.x, gridDim.x);
    const int m0 = (fid % nM) * 64;
    const int n0 = (fid / nM) * 128;

    const int srow = tid >> 2;
    const int scol = (tid & 3) * 8;
    const long arow = (long)(m0 + srow) * 1024 + scol;
    const bf16* a0 = A0 + arow;
    const bf16* a1 = SEG ? (A1 + arow) : nullptr;
    const bf16* a2 = SEG ? (A2 + arow) : nullptr;
    const bf16* bg = W + (long)z * wz + (long)(n0 + srow) * ldb + scol;

    char* asb = (char*)As;
    char* bsb = (char*)Bs;

    f32x4 acc[2][4] = {};

    const int wm = (wid >> 1) * 32;
    const int wn = (wid & 1) * 64;
    const int fr = lane & 15;
    const int kq = (lane >> 4) * 8;

    for (int k0 = 0; k0 < K; k0 += 32) {
        const bf16* ap;
        if (SEG) {
            const int seg = k0 >> 10, ko = k0 & 1023;
            ap = (seg == 0 ? a0 : (seg == 1 ? a1 : a2)) + ko;
        } else {
            ap = a0 + k0;
        }
        const bf16* bp = bg + k0;

        __syncthreads();
        gload_lds16(ap,                   asb + wid * 1024);
        gload_lds16(bp,                   bsb + wid * 1024);
        gload_lds16(bp + (long)64 * ldb,  bsb + 4096 + wid * 1024);
        __syncthreads();

        s16x8 af[2], bfv[4];
#pragma unroll
        for (int i = 0; i < 2; ++i)
            af[i] = *(const s16x8*)(As + (wm + i * 16 + fr) * 32 + kq);
#pragma unroll
        for (int i = 0; i < 4; ++i)
            bfv[i] = *(const s16x8*)(Bs + (wn + i * 16 + fr) * 32 + kq);
#pragma unroll
        for (int mi = 0; mi < 2; ++mi)
#pragma unroll
            for (int ni = 0; ni < 4; ++ni)
                acc[mi][ni] = __builtin_amdgcn_mfma_f32_16x16x32_bf16(
                    af[mi], bfv[ni], acc[mi][ni], 0, 0, 0);
    }

    const int rb = (lane >> 4) * 4;
#pragma unroll
    for (int ni = 0; ni < 4; ++ni) {
        const int col = n0 + wn + ni * 16 + fr;
        const float bv = bias ? bias[(long)z * bz + col] : 0.f;
#pragma unroll
        for (int mi = 0; mi < 2; ++mi) {
#pragma unroll
            for (int r = 0; r < 4; ++r) {
                const int row = m0 + wm + mi * 16 + rb + r;
                float v = acc[mi][ni][r] + bv;
                if (ADD) v += Add[(long)row * 1024 + col];
                if (ACT == 1) v = fmaxf(v, 0.f);
                if (ACT == 2) v = v / (1.f + __expf(-v));
                if (Cf) Cf[(long)row * ldcf + col] = v;
                if (Cb) Cb[(long)row * ldcb + col] = to_bf16(v);
            }
        }
    }
}

// ---------------- fused mask head ----------------
__global__ __launch_bounds__(64) void k_mask_softmax(
    const bf16* __restrict__ t, const float* __restrict__ W2,
    const float* __restrict__ b2, float* __restrict__ mask_out)
{
    const int tok = blockIdx.x;
    const int lane = threadIdx.x;
    float part[16];
#pragma unroll
    for (int e = 0; e < 16; ++e) part[e] = 0.f;
    const bf16* tr = t + (long)tok * 1024 + lane * 16;
#pragma unroll
    for (int kk = 0; kk < 16; ++kk) {
        float x = __bfloat162float(tr[kk]);
        const float* wr = W2 + (long)(lane * 16 + kk) * 16;
#pragma unroll
        for (int e = 0; e < 16; ++e) part[e] += x * wr[e];
    }
#pragma unroll
    for (int e = 0; e < 16; ++e) {
#pragma unroll
        for (int off = 32; off >= 1; off >>= 1)
            part[e] += __shfl_down(part[e], off);
    }
    if (lane == 0) {
        float vals[16], mx = -1e30f;
#pragma unroll
        for (int e = 0; e < 16; ++e) { vals[e] = part[e] + b2[e]; mx = fmaxf(mx, vals[e]); }
        float s = 0.f;
#pragma unroll
        for (int e = 0; e < 16; ++e) { vals[e] = __expf(vals[e] - mx); s += vals[e]; }
        float inv = 1.f / s;
#pragma unroll
        for (int e = 0; e < 16; ++e) mask_out[tok * 16 + e] = vals[e] * inv;
    }
}

// ---------------- qk = sum_e mask[tok][e] * EO[tok][e][:] -> bf16 ----------------
__global__ void k_qk(const float* __restrict__ EO, const float* __restrict__ mask,
                     bf16* __restrict__ qkb)
{
    int i = blockIdx.x * blockDim.x + threadIdx.x;
    int tok = i >> 8;
    int d4  = (i & 255) << 2;
    const float* eo = EO + (long)tok * 16384 + d4;
    const float* mk = mask + tok * 16;
    float4 s = make_float4(0.f, 0.f, 0.f, 0.f);
#pragma unroll
    for (int e = 0; e < 16; ++e) {
        float m = mk[e];
        float4 v = *(const float4*)(eo + e * 1024);
        s.x += m * v.x; s.y += m * v.y; s.z += m * v.z; s.w += m * v.w;
    }
    bf16x4_pack o{to_bf16(s.x), to_bf16(s.y), to_bf16(s.z), to_bf16(s.w)};
    ((bf16x4_pack*)qkb)[i] = o;
}

extern "C" void kernel_launch(void* const* d_in, const int* in_sizes, int n_in,
                              void* d_out, int out_size, void* d_ws, size_t ws_size,
                              hipStream_t stream)
{
    const int Mtok = 4096, D = 1024, E = 16, V = 32000, DIN = 3072;

    const float* L      = (const float*)d_in[0];
    const float* mL     = (const float*)d_in[1];
    const float* prompt = (const float*)d_in[2];
    const float* noise  = (const float*)d_in[3];
    const float* qa_W1 = (const float*)d_in[4];  const float* qa_b1 = (const float*)d_in[5];
    const float* qa_W2 = (const float*)d_in[6];  const float* qa_b2 = (const float*)d_in[7];
    const float* qb_W1 = (const float*)d_in[8];  const float* qb_b1 = (const float*)d_in[9];
    const float* qb_W2 = (const float*)d_in[10]; const float* qb_b2 = (const float*)d_in[11];
    const float* qc_W1 = (const float*)d_in[12]; const float* qc_b1 = (const float*)d_in[13];
    const float* qc_W2 = (const float*)d_in[14]; const float* qc_b2 = (const float*)d_in[15];
    const float* ek_W1 = (const float*)d_in[16]; const float* ek_b1 = (const float*)d_in[17];
    const float* ek_W2 = (const float*)d_in[18]; const float* ek_b2 = (const float*)d_in[19];
    const float* md_W1 = (const float*)d_in[20]; const float* md_b1 = (const float*)d_in[21];
    const float* md_W2 = (const float*)d_in[22]; const float* md_b2 = (const float*)d_in[23];
    const float* td_W  = (const float*)d_in[24]; const float* td_b  = (const float*)d_in[25];

    float* out = (float*)d_out;
    float* out_L2   = out;
    float* out_mLp  = out + 4194304;
    float* out_mask = out + 8388608;
    float* out_txt  = out + 8454144;
    float* out_EO   = out + 139526144;

    char* ws = (char*)d_ws;
    size_t off = 0;
    auto alloc = [&](size_t bytes) -> void* {
        void* p = ws + off;
        off += (bytes + 255) & ~(size_t)255;
        return p;
    };

    bf16* wqa1 = (bf16*)alloc((size_t)DIN * D * 2);
    bf16* wqa2 = (bf16*)alloc((size_t)D * D * 2);
    bf16* wqb1 = (bf16*)alloc((size_t)DIN * D * 2);
    bf16* wqb2 = (bf16*)alloc((size_t)D * D * 2);
    bf16* wqc1 = (bf16*)alloc((size_t)DIN * D * 2);
    bf16* wqc2 = (bf16*)alloc((size_t)D * D * 2);
    bf16* wmd1 = (bf16*)alloc((size_t)D * D * 2);
    bf16* wek1 = (bf16*)alloc((size_t)E * D * D * 2);
    bf16* wek2 = (bf16*)alloc((size_t)E * D * D * 2);
    bf16* wtd  = (bf16*)alloc((size_t)D * V * 2);

    bf16* Lb   = (bf16*)alloc((size_t)Mtok * D * 2);
    bf16* mLb  = (bf16*)alloc((size_t)Mtok * D * 2);
    bf16* Pb   = (bf16*)alloc((size_t)Mtok * D * 2);
    bf16* Nb   = (bf16*)alloc((size_t)Mtok * D * 2);
    bf16* hbuf = (bf16*)alloc((size_t)Mtok * D * 2);
    bf16* L1b  = (bf16*)alloc((size_t)Mtok * D * 2);
    bf16* sLb  = (bf16*)alloc((size_t)Mtok * D * 2);
    bf16* tb   = (bf16*)alloc((size_t)Mtok * D * 2);
    bf16* qkb  = (bf16*)alloc((size_t)Mtok * D * 2);
    bf16* L2b  = (bf16*)alloc((size_t)Mtok * D * 2);
    float* paf = (float*)alloc((size_t)Mtok * D * 4);   // qa shared partial (fp32)

    const size_t hall_bytes = (size_t)E * Mtok * D * 2;
    bool batched = (off + hall_bytes + 256 <= ws_size);
    bf16* hall = batched ? (bf16*)alloc(hall_bytes) : nullptr;

    // fused activation conversions (1 launch)
    k_conv4<<<dim3(4 * 1048576 / 256), dim3(256), 0, stream>>>(
        L, mL, prompt, noise, Lb, mLb, Pb, Nb);

    // weight transposes (3 launches)
    k_transpose_3k<<<dim3(32, 96, 3), dim3(256), 0, stream>>>(
        qa_W1, qb_W1, qc_W1, wqa1, wqb1, wqc1);
    k_transpose_1k<<<dim3(32, 32, 36), dim3(256), 0, stream>>>(
        qa_W2, qb_W2, qc_W2, md_W1, ek_W1, ek_W2,
        wqa2, wqb2, wqc2, wmd1, wek1, wek2);
    k_transpose_f32_bf16<<<dim3(V / 32, D / 32), dim3(256), 0, stream>>>(td_W, wtd, D, V);

    const int nM128 = Mtok / 128;               // 32
    dim3 gph(nM128 * (D / 128), 1, 1);          // 256 WGs
    dim3 bph(512);

    // pa = prompt @ qaW1b + mL @ qaW1c   (K=2048, fp32 out)
    k_gemm128ph<0, 1, 0, 1, 0><<<gph, bph, 0, stream>>>(
        Pb, mLb, mLb, wqa1 + 1024, DIN, nullptr, nullptr,
        paf, D, nullptr, 0, 2048, nM128);

    // L1 = qa([L | prompt | mL]) : h = relu(L@W1a + pa + b1); L1 = h@W2 + b2
    k_gemm128ph<1, 0, 1, 0, 1><<<gph, bph, 0, stream>>>(
        Lb, Lb, Lb, wqa1, DIN, qa_b1, paf,
        nullptr, 0, hbuf, D, 1024, nM128);
    k_gemm128ph<0, 0, 0, 0, 1><<<gph, bph, 0, stream>>>(
        hbuf, hbuf, hbuf, wqa2, D, qa_b2, nullptr,
        nullptr, 0, L1b, D, 1024, nM128);

    // sL = qb([noise | prompt | L1])
    k_gemm128ph<1, 1, 0, 0, 1><<<gph, bph, 0, stream>>>(
        Nb, Pb, L1b, wqb1, DIN, qb_b1, nullptr,
        nullptr, 0, hbuf, D, 3072, nM128);
    k_gemm128ph<0, 0, 0, 0, 1><<<gph, bph, 0, stream>>>(
        hbuf, hbuf, hbuf, wqb2, D, qb_b2, nullptr,
        nullptr, 0, sLb, D, 1024, nM128);

    // mask = softmax(relu(sL @ md_W1 + b1) @ md_W2 + b2)
    k_gemm128ph<1, 0, 0, 0, 1><<<gph, bph, 0, stream>>>(
        sLb, sLb, sLb, wmd1, D, md_b1, nullptr,
        nullptr, 0, tb, D, 1024, nM128);
    k_mask_softmax<<<dim3(Mtok), dim3(64), 0, stream>>>(tb, md_W2, md_b2, out_mask);

    // experts via 256^2 phased kernel (z=16)
    if (batched) {
        dim3 ge(16 * 4, 1, 16), be(512);
        k_gemm256<2, 0, 1><<<ge, be, 0, stream>>>(
            L1b, D, 0, wek1, (long)D * D, ek_b1, D,
            nullptr, 0, 0, hall, D, (long)Mtok * D, D, 4);
        k_gemm256<0, 1, 0><<<ge, be, 0, stream>>>(
            hall, D, (long)Mtok * D, wek2, (long)D * D, ek_b2, D,
            out_EO, E * D, D, nullptr, 0, 0, D, 4);
    } else {
        dim3 b64(256);
        const int nM64 = Mtok / 64;
        dim3 g64(nM64 * (D / 128), 1, 1);
        for (int e = 0; e < 16; ++e) {
            k_gemm64<2, 0, 0><<<g64, b64, 0, stream>>>(
                L1b, L1b, L1b, wek1 + (size_t)e * D * D, D, 0, ek_b1 + e * D, 0, nullptr,
                nullptr, 0, hbuf, D, 1024, nM64);
            k_gemm64<0, 0, 0><<<g64, b64, 0, stream>>>(
                hbuf, hbuf, hbuf, wek2 + (size_t)e * D * D, D, 0, ek_b2 + e * D, 0, nullptr,
                out_EO + e * D, E * D, nullptr, 0, 1024, nM64);
        }
    }

    // qk = sum_e mask * EO
    k_qk<<<dim3(4096), dim3(256), 0, stream>>>(out_EO, out_mask, qkb);

    // L2 = qa([qk | prompt | mL]) : h = relu(qk@W1a + pa + b1); L2 = h@W2 + b2
    k_gemm128ph<1, 0, 1, 0, 1><<<gph, bph, 0, stream>>>(
        qkb, qkb, qkb, wqa1, DIN, qa_b1, paf,
        nullptr, 0, hbuf, D, 1024, nM128);
    k_gemm128ph<0, 0, 0, 1, 1><<<gph, bph, 0, stream>>>(
        hbuf, hbuf, hbuf, wqa2, D, qa_b2, nullptr,
        out_L2, D, L2b, D, 1024, nM128);

    // mL_pred = qc([mL | prompt | L2])
    k_gemm128ph<1, 1, 0, 0, 1><<<gph, bph, 0, stream>>>(
        mLb, Pb, L2b, wqc1, DIN, qc_b1, nullptr,
        nullptr, 0, hbuf, D, 3072, nM128);
    k_gemm128ph<0, 0, 0, 1, 0><<<gph, bph, 0, stream>>>(
        hbuf, hbuf, hbuf, wqc2, D, qc_b2, nullptr,
        out_mLp, D, nullptr, 0, 1024, nM128);

    // text_logits = L2 @ td_W + td_b  (256^2 phased)
    {
        dim3 gl(16 * 125, 1, 1), bl(512);
        k_gemm256<0, 1, 0><<<gl, bl, 0, stream>>>(
            L2b, D, 0, wtd, 0, td_b, 0,
            out_txt, V, 0, nullptr, 0, 0, D, 125);
    }
}

// Round 9
// 1108.460 us; speedup vs baseline: 1.4891x; 1.0544x over previous
//
#include <hip/hip_runtime.h>
#include <hip/hip_bf16.h>
#include <cstdint>
#include <cstddef>

using bf16 = __hip_bfloat16;

typedef __attribute__((ext_vector_type(4))) float f32x4;
typedef __attribute__((ext_vector_type(8))) short s16x8;

__device__ __forceinline__ bf16 to_bf16(float v) { return __float2bfloat16(v); }

struct alignas(8) bf16x4_pack { bf16 x, y, z, w; };

// bijective XCD-chunking swizzle (m204)
__device__ __forceinline__ int xcd_swz(int orig, int nwg) {
    int xcd = orig & 7, base = orig >> 3;
    int q = nwg >> 3, r = nwg & 7;
    return (xcd < r ? xcd * (q + 1) : r * (q + 1) + (xcd - r) * q) + base;
}

#define BAR()        asm volatile("s_barrier" ::: "memory")
#define WAITV4_BAR() asm volatile("s_waitcnt vmcnt(4)\ns_barrier" ::: "memory")
#define WAITV0_BAR() asm volatile("s_waitcnt vmcnt(0)\ns_barrier" ::: "memory")

// ---------------- fused fp32 -> bf16 conversion of the 4 activation inputs ----------------
__global__ void k_conv4(const float* __restrict__ a, const float* __restrict__ b,
                        const float* __restrict__ c, const float* __restrict__ d,
                        bf16* __restrict__ oa, bf16* __restrict__ ob,
                        bf16* __restrict__ oc, bf16* __restrict__ od)
{
    int i = blockIdx.x * blockDim.x + threadIdx.x;      // 4 * 1048576 units of 4 floats
    int sel = i >> 20, li = i & 1048575;
    const float* src = sel == 0 ? a : (sel == 1 ? b : (sel == 2 ? c : d));
    bf16* dst = sel == 0 ? oa : (sel == 1 ? ob : (sel == 2 ? oc : od));
    float4 v = ((const float4*)src)[li];
    bf16x4_pack o{to_bf16(v.x), to_bf16(v.y), to_bf16(v.z), to_bf16(v.w)};
    ((bf16x4_pack*)dst)[li] = o;
}

// ---------------- fp32 [K][N] -> bf16 [N][K] tiled transpose (single job) ----------------
__global__ __launch_bounds__(256) void k_transpose_f32_bf16(
    const float* __restrict__ in, bf16* __restrict__ out, int K, int N)
{
    __shared__ float t[32][33];
    int n0 = blockIdx.x * 32, k0 = blockIdx.y * 32;
    int tx = threadIdx.x & 31, ty = threadIdx.x >> 5;
#pragma unroll
    for (int r = 0; r < 32; r += 8)
        t[ty + r][tx] = in[(long)(k0 + ty + r) * N + (n0 + tx)];
    __syncthreads();
#pragma unroll
    for (int r = 0; r < 32; r += 8)
        out[(long)(n0 + ty + r) * K + (k0 + tx)] = to_bf16(t[tx][ty + r]);
}

// ---------------- multi-job transposes: 36 x (1024x1024) jobs, z-indexed ----------------
__global__ __launch_bounds__(256) void k_transpose_1k(
    const float* __restrict__ s0, const float* __restrict__ s1,
    const float* __restrict__ s2, const float* __restrict__ s3,
    const float* __restrict__ ek1, const float* __restrict__ ek2,
    bf16* __restrict__ d0, bf16* __restrict__ d1,
    bf16* __restrict__ d2, bf16* __restrict__ d3,
    bf16* __restrict__ dk1, bf16* __restrict__ dk2)
{
    __shared__ float t[32][33];
    const int z = blockIdx.z;
    const float* in; bf16* out;
    if (z < 4) {
        in  = z == 0 ? s0 : (z == 1 ? s1 : (z == 2 ? s2 : s3));
        out = z == 0 ? d0 : (z == 1 ? d1 : (z == 2 ? d2 : d3));
    } else if (z < 20) {
        in = ek1 + (long)(z - 4) * 1048576;  out = dk1 + (long)(z - 4) * 1048576;
    } else {
        in = ek2 + (long)(z - 20) * 1048576; out = dk2 + (long)(z - 20) * 1048576;
    }
    int n0 = blockIdx.x * 32, k0 = blockIdx.y * 32;
    int tx = threadIdx.x & 31, ty = threadIdx.x >> 5;
#pragma unroll
    for (int r = 0; r < 32; r += 8)
        t[ty + r][tx] = in[(long)(k0 + ty + r) * 1024 + (n0 + tx)];
    __syncthreads();
#pragma unroll
    for (int r = 0; r < 32; r += 8)
        out[(long)(n0 + ty + r) * 1024 + (k0 + tx)] = to_bf16(t[tx][ty + r]);
}

// ---------------- multi-job transposes: 3 x (3072x1024) jobs ----------------
__global__ __launch_bounds__(256) void k_transpose_3k(
    const float* __restrict__ s0, const float* __restrict__ s1, const float* __restrict__ s2,
    bf16* __restrict__ d0, bf16* __restrict__ d1, bf16* __restrict__ d2)
{
    __shared__ float t[32][33];
    const int z = blockIdx.z;
    const float* in = z == 0 ? s0 : (z == 1 ? s1 : s2);
    bf16* out = z == 0 ? d0 : (z == 1 ? d1 : d2);
    int n0 = blockIdx.x * 32, k0 = blockIdx.y * 32;
    int tx = threadIdx.x & 31, ty = threadIdx.x >> 5;
#pragma unroll
    for (int r = 0; r < 32; r += 8)
        t[ty + r][tx] = in[(long)(k0 + ty + r) * 1024 + (n0 + tx)];
    __syncthreads();
#pragma unroll
    for (int r = 0; r < 32; r += 8)
        out[(long)(n0 + ty + r) * 3072 + (k0 + tx)] = to_bf16(t[tx][ty + r]);
}

// ---------------- async global->LDS 16B helper ----------------
__device__ __forceinline__ void gload_lds16(const void* g, void* l) {
    __builtin_amdgcn_global_load_lds(
        (const __attribute__((address_space(1))) void*)g,
        (__attribute__((address_space(3))) void*)l,
        16, 0, 0);
}

// ================= 256x256 BK=64 8-wave phased GEMM (proven cadence) =================
// Round 9: vectorized epilogue — per-wave LDS transpose staging, dwordx4/dwordx2 stores.
template<int ACT, int OUTF, int OUTB>   // ACT: 0 none, 1 relu, 2 silu
__global__ __launch_bounds__(512, 2) void k_gemm256(
    const bf16* __restrict__ A, int lda, long az,
    const bf16* __restrict__ W, long wz,
    const float* __restrict__ bias, long bz,
    float* __restrict__ Cf, int ldcf, long cfz,
    bf16* __restrict__ Cb, int ldcb, long cbz,
    int K, int nN)
{
    __shared__ char lds[131072];
    const int tid = threadIdx.x;
    const int wid = tid >> 6, lane = tid & 63;
    const int z = blockIdx.z;
    const int fid = xcd_swz(blockIdx.x, gridDim.x);
    const int m0 = (fid / nN) * 256;
    const int n0 = (fid % nN) * 256;
    const int wr = wid >> 2, wc = wid & 3;

    const int srow = tid >> 2;
    const int sk   = ((tid & 3) ^ (srow & 3)) * 8;
    const bf16* Ag = A + (long)z * az + (long)(m0 + srow) * lda + sk;
    const bf16* Wg = W + (long)z * wz + (long)(n0 + srow) * K + sk;

    const int fr = lane & 15;
    const int xorv = (((lane >> 4) ^ (lane & 3)) << 4);
    const int aRd = wr * 16384 + fr * 64 + xorv;
    const int bRd = 65536 + (wc >> 1) * 16384 + ((wc & 1) << 12) + fr * 64 + xorv;

    f32x4 acc[8][4] = {};
    const int NT = K >> 6;

    auto issueA = [&](int db, int kh, int kb) {
        char* l = lds + db * 32768 + kh * 8192 + wid * 1024;
        gload_lds16(Ag + kb + kh * 32, l);
        gload_lds16(Ag + kb + kh * 32 + (long)128 * lda, l + 16384);
    };
    auto issueB = [&](int db, int kh, int kb) {
        char* l = lds + 65536 + db * 32768 + kh * 8192 + wid * 1024;
        gload_lds16(Wg + kb + kh * 32, l);
        gload_lds16(Wg + kb + kh * 32 + (long)128 * K, l + 16384);
    };

    issueA(0, 0, 0); issueB(0, 0, 0);
    issueA(0, 1, 0); issueB(0, 1, 0);
    WAITV4_BAR();

    for (int t = 0; t < NT; ++t) {
        const int db = t & 1, nb = db ^ 1;
        const int kn = (t + 1) << 6;
        const bool pf = (t + 1 < NT);
        const int abase = aRd + db * 32768;
        const int bbase = bRd + db * 32768;
        s16x8 a[4], b[4];

#pragma unroll
        for (int i = 0; i < 4; ++i) b[i] = *(const s16x8*)(lds + bbase + i * 1024);
#pragma unroll
        for (int i = 0; i < 4; ++i) a[i] = *(const s16x8*)(lds + abase + i * 1024);
        if (pf) issueA(nb, 0, kn);
        BAR();
        __builtin_amdgcn_s_setprio(1);
#pragma unroll
        for (int mi = 0; mi < 4; ++mi)
#pragma unroll
            for (int ni = 0; ni < 4; ++ni)
                acc[mi][ni] = __builtin_amdgcn_mfma_f32_16x16x32_bf16(a[mi], b[ni], acc[mi][ni], 0, 0, 0);
        __builtin_amdgcn_s_setprio(0);
        BAR();

#pragma unroll
        for (int i = 0; i < 4; ++i) a[i] = *(const s16x8*)(lds + abase + (4 + i) * 1024);
        if (pf) issueB(nb, 0, kn);
        BAR();
        __builtin_amdgcn_s_setprio(1);
#pragma unroll
        for (int mi = 0; mi < 4; ++mi)
#pragma unroll
            for (int ni = 0; ni < 4; ++ni)
                acc[4 + mi][ni] = __builtin_amdgcn_mfma_f32_16x16x32_bf16(a[mi], b[ni], acc[4 + mi][ni], 0, 0, 0);
        __builtin_amdgcn_s_setprio(0);
        if (pf) { WAITV4_BAR(); }
        else    { WAITV0_BAR(); }

#pragma unroll
        for (int i = 0; i < 4; ++i) b[i] = *(const s16x8*)(lds + bbase + 8192 + i * 1024);
#pragma unroll
        for (int i = 0; i < 4; ++i) a[i] = *(const s16x8*)(lds + abase + 8192 + i * 1024);
        if (pf) issueA(nb, 1, kn);
        BAR();
        __builtin_amdgcn_s_setprio(1);
#pragma unroll
        for (int mi = 0; mi < 4; ++mi)
#pragma unroll
            for (int ni = 0; ni < 4; ++ni)
                acc[mi][ni] = __builtin_amdgcn_mfma_f32_16x16x32_bf16(a[mi], b[ni], acc[mi][ni], 0, 0, 0);
        __builtin_amdgcn_s_setprio(0);
        BAR();

#pragma unroll
        for (int i = 0; i < 4; ++i) a[i] = *(const s16x8*)(lds + abase + 8192 + (4 + i) * 1024);
        if (pf) issueB(nb, 1, kn);
        BAR();
        __builtin_amdgcn_s_setprio(1);
#pragma unroll
        for (int mi = 0; mi < 4; ++mi)
#pragma unroll
            for (int ni = 0; ni < 4; ++ni)
                acc[4 + mi][ni] = __builtin_amdgcn_mfma_f32_16x16x32_bf16(a[mi], b[ni], acc[4 + mi][ni], 0, 0, 0);
        __builtin_amdgcn_s_setprio(0);
        if (pf) { WAITV4_BAR(); }
    }

    // ---- vectorized epilogue: per-wave LDS transpose staging ----
    __syncthreads();   // main-loop LDS traffic fully drained before reuse
    float* scb = (float*)(lds + wid * 16384);   // wave-private 16KB; 2 x 4KB chunks used
    const int rb = (lane >> 4) * 4;
    const int rrow = lane >> 4;          // read row-in-group 0..3
    const int rcol = (lane & 15) * 4;    // read col 0..60
    const int colv = n0 + wc * 64 + rcol;
    float4 bv4 = *(const float4*)(bias + (long)z * bz + colv);
#pragma unroll
    for (int mi = 0; mi < 8; ++mi) {
        float* sc = scb + (mi & 1) * 1024;    // alternate 4KB chunks
#pragma unroll
        for (int ni = 0; ni < 4; ++ni)
#pragma unroll
            for (int r = 0; r < 4; ++r)
                sc[(rb + r) * 64 + ni * 16 + fr] = acc[mi][ni][r];
        asm volatile("s_waitcnt lgkmcnt(0)" ::: "memory");   // wave-local writes visible
#pragma unroll
        for (int it = 0; it < 4; ++it) {
            const int row = m0 + wr * 128 + mi * 16 + it * 4 + rrow;
            f32x4 v4 = *(const f32x4*)(sc + (it * 4 + rrow) * 64 + rcol);
            float vv[4];
#pragma unroll
            for (int j = 0; j < 4; ++j) {
                float v = v4[j] + (&bv4.x)[j];
                if (ACT == 1) v = fmaxf(v, 0.f);
                if (ACT == 2) v = v / (1.f + __expf(-v));
                vv[j] = v;
            }
            if (OUTF)
                *(float4*)(Cf + (long)z * cfz + (long)row * ldcf + colv) =
                    make_float4(vv[0], vv[1], vv[2], vv[3]);
            if (OUTB) {
                bf16x4_pack o{to_bf16(vv[0]), to_bf16(vv[1]), to_bf16(vv[2]), to_bf16(vv[3])};
                *(bf16x4_pack*)(Cb + (long)z * cbz + (long)row * ldcb + colv) = o;
            }
        }
    }
}

// ================= 128x128 BK=128 8-wave phased GEMM, 2 merged phases/K-tile =================
template<int ACT, int SEG, int ADD, int OUTF, int OUTB>
__global__ __launch_bounds__(512, 2) void k_gemm128ph(
    const bf16* __restrict__ A0, const bf16* __restrict__ A1, const bf16* __restrict__ A2,
    const bf16* __restrict__ W, int ldb,
    const float* __restrict__ bias,
    const float* __restrict__ Add,
    float* __restrict__ Cf, int ldcf,
    bf16* __restrict__ Cb, int ldcb,
    int K, int nM)
{
    __shared__ char lds[131072];
    const int tid = threadIdx.x;
    const int wid = tid >> 6, lane = tid & 63;
    const int fid = xcd_swz(blockIdx.x, gridDim.x);
    const int m0 = (fid % nM) * 128;
    const int n0 = (fid / nM) * 128;
    const int wr = wid >> 1, wc = wid & 1;

    const int trow = tid >> 3;
    const int swzc = ((tid & 7) ^ (trow & 7)) * 8;
    const long aoff0 = (long)(m0 + trow) * 1024 + swzc;
    const long aoff1 = aoff0 + (long)64 * 1024;
    const long boff0 = (long)(n0 + trow) * ldb + swzc;
    const long boff1 = boff0 + (long)64 * ldb;

    const int fr = lane & 15, g = lane >> 4;
    const int ch0 = ((g ^ (fr & 7)) << 4);
    const int ch1 = (((4 + g) ^ (fr & 7)) << 4);
    const int arow = (wr * 32 + fr) * 128;
    const int brow = 65536 + (wc * 64 + fr) * 128;

    f32x4 acc[2][4] = {};
    const int NT = K >> 7;

    auto issueA = [&](int db, int kh, const bf16* base, int ko) {
        char* l = lds + db * 32768 + kh * 16384 + wid * 1024;
        gload_lds16(base + aoff0 + ko + kh * 64, l);
        gload_lds16(base + aoff1 + ko + kh * 64, l + 8192);
    };
    auto issueB = [&](int db, int kh, int kfull) {
        char* l = lds + 65536 + db * 32768 + kh * 16384 + wid * 1024;
        gload_lds16(W + boff0 + kfull + kh * 64, l);
        gload_lds16(W + boff1 + kfull + kh * 64, l + 8192);
    };
    auto aseg = [&](int k0, const bf16*& base, int& ko) {
        if (SEG) { int s = k0 >> 10; base = (s == 0 ? A0 : (s == 1 ? A1 : A2)); ko = k0 & 1023; }
        else     { base = A0; ko = k0; }
    };

    { const bf16* b0; int k0o; aseg(0, b0, k0o);
      issueA(0, 0, b0, k0o); issueB(0, 0, 0);
      issueA(0, 1, b0, k0o); issueB(0, 1, 0); }
    WAITV4_BAR();

    for (int t = 0; t < NT; ++t) {
        const int db = t & 1, nb = db ^ 1;
        const int kn = (t + 1) << 7;
        const bool pf = (t + 1 < NT);
        const bf16* nab = A0; int nko = 0;
        if (pf) aseg(kn, nab, nko);
        const int ab = db * 32768, bb = db * 32768;
        s16x8 a0[2], a1[2], b0[4], b1[4];

#pragma unroll
        for (int i = 0; i < 4; ++i) b0[i] = *(const s16x8*)(lds + bb + brow + i * 2048 + ch0);
#pragma unroll
        for (int i = 0; i < 4; ++i) b1[i] = *(const s16x8*)(lds + bb + brow + i * 2048 + ch1);
#pragma unroll
        for (int i = 0; i < 2; ++i) a0[i] = *(const s16x8*)(lds + ab + arow + i * 2048 + ch0);
#pragma unroll
        for (int i = 0; i < 2; ++i) a1[i] = *(const s16x8*)(lds + ab + arow + i * 2048 + ch1);
        if (pf) { issueA(nb, 0, nab, nko); issueB(nb, 0, kn); }
        BAR();
        __builtin_amdgcn_s_setprio(1);
#pragma unroll
        for (int mi = 0; mi < 2; ++mi)
#pragma unroll
            for (int ni = 0; ni < 4; ++ni)
                acc[mi][ni] = __builtin_amdgcn_mfma_f32_16x16x32_bf16(a0[mi], b0[ni], acc[mi][ni], 0, 0, 0);
#pragma unroll
        for (int mi = 0; mi < 2; ++mi)
#pragma unroll
            for (int ni = 0; ni < 4; ++ni)
                acc[mi][ni] = __builtin_amdgcn_mfma_f32_16x16x32_bf16(a1[mi], b1[ni], acc[mi][ni], 0, 0, 0);
        __builtin_amdgcn_s_setprio(0);
        if (pf) { WAITV4_BAR(); }
        else    { WAITV0_BAR(); }

#pragma unroll
        for (int i = 0; i < 4; ++i) b0[i] = *(const s16x8*)(lds + bb + 16384 + brow + i * 2048 + ch0);
#pragma unroll
        for (int i = 0; i < 4; ++i) b1[i] = *(const s16x8*)(lds + bb + 16384 + brow + i * 2048 + ch1);
#pragma unroll
        for (int i = 0; i < 2; ++i) a0[i] = *(const s16x8*)(lds + ab + 16384 + arow + i * 2048 + ch0);
#pragma unroll
        for (int i = 0; i < 2; ++i) a1[i] = *(const s16x8*)(lds + ab + 16384 + arow + i * 2048 + ch1);
        if (pf) { issueA(nb, 1, nab, nko); issueB(nb, 1, kn); }
        BAR();
        __builtin_amdgcn_s_setprio(1);
#pragma unroll
        for (int mi = 0; mi < 2; ++mi)
#pragma unroll
            for (int ni = 0; ni < 4; ++ni)
                acc[mi][ni] = __builtin_amdgcn_mfma_f32_16x16x32_bf16(a0[mi], b0[ni], acc[mi][ni], 0, 0, 0);
#pragma unroll
        for (int mi = 0; mi < 2; ++mi)
#pragma unroll
            for (int ni = 0; ni < 4; ++ni)
                acc[mi][ni] = __builtin_amdgcn_mfma_f32_16x16x32_bf16(a1[mi], b1[ni], acc[mi][ni], 0, 0, 0);
        __builtin_amdgcn_s_setprio(0);
        if (pf) { WAITV4_BAR(); }
    }

    const int rb = g * 4;
#pragma unroll
    for (int ni = 0; ni < 4; ++ni) {
        const int col = n0 + wc * 64 + ni * 16 + fr;
        const float bv = bias ? bias[col] : 0.f;
#pragma unroll
        for (int mi = 0; mi < 2; ++mi) {
#pragma unroll
            for (int r = 0; r < 4; ++r) {
                const int row = m0 + wr * 32 + mi * 16 + rb + r;
                float v = acc[mi][ni][r] + bv;
                if (ADD) v += Add[(long)row * 1024 + col];
                if (ACT == 1) v = fmaxf(v, 0.f);
                if (ACT == 2) v = v / (1.f + __expf(-v));
                if (OUTF) Cf[(long)row * ldcf + col] = v;
                if (OUTB) Cb[(long)row * ldcb + col] = to_bf16(v);
            }
        }
    }
}

// ================= 64x128 m97-style GEMM (fallback path only) =================
template<int ACT, int SEG, int ADD>
__global__ __launch_bounds__(256, 4) void k_gemm64(
    const bf16* __restrict__ A0, const bf16* __restrict__ A1, const bf16* __restrict__ A2,
    const bf16* __restrict__ W, int ldb, long wz,
    const float* __restrict__ bias, long bz,
    const float* __restrict__ Add,
    float* __restrict__ Cf, int ldcf,
    bf16* __restrict__ Cb, int ldcb,
    int K, int nM)
{
    __shared__ bf16 As[64 * 32];
    __shared__ bf16 Bs[128 * 32];
    const int tid  = threadIdx.x;
    const int wid  = tid >> 6;
    const int lane = tid & 63;
    const int z = blockIdx.z;

    const int fid = xcd_swz(blockIdx.x, gridDim.x);
    const int m0 = (fid % nM) * 64;
    const int n0 = (fid / nM) * 128;

    const int srow = tid >> 2;
    const int scol = (tid & 3) * 8;
    const long arow = (long)(m0 + srow) * 1024 + scol;
    const bf16* a0 = A0 + arow;
    const bf16* a1 = SEG ? (A1 + arow) : nullptr;
    const bf16* a2 = SEG ? (A2 + arow) : nullptr;
    const bf16* bg = W + (long)z * wz + (long)(n0 + srow) * ldb + scol;

    char* asb = (char*)As;
    char* bsb = (char*)Bs;

    f32x4 acc[2][4] = {};

    const int wm = (wid >> 1) * 32;
    const int wn = (wid & 1) * 64;
    const int fr = lane & 15;
    const int kq = (lane >> 4) * 8;

    for (int k0 = 0; k0 < K; k0 += 32) {
        const bf16* ap;
        if (SEG) {
            const int seg = k0 >> 10, ko = k0 & 1023;
            ap = (seg == 0 ? a0 : (seg == 1 ? a1 : a2)) + ko;
        } else {
            ap = a0 + k0;
        }
        const bf16* bp = bg + k0;

        __syncthreads();
        gload_lds16(ap,                   asb + wid * 1024);
        gload_lds16(bp,                   bsb + wid * 1024);
        gload_lds16(bp + (long)64 * ldb,  bsb + 4096 + wid * 1024);
        __syncthreads();

        s16x8 af[2], bfv[4];
#pragma unroll
        for (int i = 0; i < 2; ++i)
            af[i] = *(const s16x8*)(As + (wm + i * 16 + fr) * 32 + kq);
#pragma unroll
        for (int i = 0; i < 4; ++i)
            bfv[i] = *(const s16x8*)(Bs + (wn + i * 16 + fr) * 32 + kq);
#pragma unroll
        for (int mi = 0; mi < 2; ++mi)
#pragma unroll
            for (int ni = 0; ni < 4; ++ni)
                acc[mi][ni] = __builtin_amdgcn_mfma_f32_16x16x32_bf16(
                    af[mi], bfv[ni], acc[mi][ni], 0, 0, 0);
    }

    const int rb = (lane >> 4) * 4;
#pragma unroll
    for (int ni = 0; ni < 4; ++ni) {
        const int col = n0 + wn + ni * 16 + fr;
        const float bv = bias ? bias[(long)z * bz + col] : 0.f;
#pragma unroll
        for (int mi = 0; mi < 2; ++mi) {
#pragma unroll
            for (int r = 0; r < 4; ++r) {
                const int row = m0 + wm + mi * 16 + rb + r;
                float v = acc[mi][ni][r] + bv;
                if (ADD) v += Add[(long)row * 1024 + col];
                if (ACT == 1) v = fmaxf(v, 0.f);
                if (ACT == 2) v = v / (1.f + __expf(-v));
                if (Cf) Cf[(long)row * ldcf + col] = v;
                if (Cb) Cb[(long)row * ldcb + col] = to_bf16(v);
            }
        }
    }
}

// ---------------- fused mask head ----------------
__global__ __launch_bounds__(64) void k_mask_softmax(
    const bf16* __restrict__ t, const float* __restrict__ W2,
    const float* __restrict__ b2, float* __restrict__ mask_out)
{
    const int tok = blockIdx.x;
    const int lane = threadIdx.x;
    float part[16];
#pragma unroll
    for (int e = 0; e < 16; ++e) part[e] = 0.f;
    const bf16* tr = t + (long)tok * 1024 + lane * 16;
#pragma unroll
    for (int kk = 0; kk < 16; ++kk) {
        float x = __bfloat162float(tr[kk]);
        const float* wr = W2 + (long)(lane * 16 + kk) * 16;
#pragma unroll
        for (int e = 0; e < 16; ++e) part[e] += x * wr[e];
    }
#pragma unroll
    for (int e = 0; e < 16; ++e) {
#pragma unroll
        for (int off = 32; off >= 1; off >>= 1)
            part[e] += __shfl_down(part[e], off);
    }
    if (lane == 0) {
        float vals[16], mx = -1e30f;
#pragma unroll
        for (int e = 0; e < 16; ++e) { vals[e] = part[e] + b2[e]; mx = fmaxf(mx, vals[e]); }
        float s = 0.f;
#pragma unroll
        for (int e = 0; e < 16; ++e) { vals[e] = __expf(vals[e] - mx); s += vals[e]; }
        float inv = 1.f / s;
#pragma unroll
        for (int e = 0; e < 16; ++e) mask_out[tok * 16 + e] = vals[e] * inv;
    }
}

// ---------------- qk = sum_e mask[tok][e] * EO[tok][e][:] -> bf16 ----------------
__global__ void k_qk(const float* __restrict__ EO, const float* __restrict__ mask,
                     bf16* __restrict__ qkb)
{
    int i = blockIdx.x * blockDim.x + threadIdx.x;
    int tok = i >> 8;
    int d4  = (i & 255) << 2;
    const float* eo = EO + (long)tok * 16384 + d4;
    const float* mk = mask + tok * 16;
    float4 s = make_float4(0.f, 0.f, 0.f, 0.f);
#pragma unroll
    for (int e = 0; e < 16; ++e) {
        float m = mk[e];
        float4 v = *(const float4*)(eo + e * 1024);
        s.x += m * v.x; s.y += m * v.y; s.z += m * v.z; s.w += m * v.w;
    }
    bf16x4_pack o{to_bf16(s.x), to_bf16(s.y), to_bf16(s.z), to_bf16(s.w)};
    ((bf16x4_pack*)qkb)[i] = o;
}

extern "C" void kernel_launch(void* const* d_in, const int* in_sizes, int n_in,
                              void* d_out, int out_size, void* d_ws, size_t ws_size,
                              hipStream_t stream)
{
    const int Mtok = 4096, D = 1024, E = 16, V = 32000, DIN = 3072;

    const float* L      = (const float*)d_in[0];
    const float* mL     = (const float*)d_in[1];
    const float* prompt = (const float*)d_in[2];
    const float* noise  = (const float*)d_in[3];
    const float* qa_W1 = (const float*)d_in[4];  const float* qa_b1 = (const float*)d_in[5];
    const float* qa_W2 = (const float*)d_in[6];  const float* qa_b2 = (const float*)d_in[7];
    const float* qb_W1 = (const float*)d_in[8];  const float* qb_b1 = (const float*)d_in[9];
    const float* qb_W2 = (const float*)d_in[10]; const float* qb_b2 = (const float*)d_in[11];
    const float* qc_W1 = (const float*)d_in[12]; const float* qc_b1 = (const float*)d_in[13];
    const float* qc_W2 = (const float*)d_in[14]; const float* qc_b2 = (const float*)d_in[15];
    const float* ek_W1 = (const float*)d_in[16]; const float* ek_b1 = (const float*)d_in[17];
    const float* ek_W2 = (const float*)d_in[18]; const float* ek_b2 = (const float*)d_in[19];
    const float* md_W1 = (const float*)d_in[20]; const float* md_b1 = (const float*)d_in[21];
    const float* md_W2 = (const float*)d_in[22]; const float* md_b2 = (const float*)d_in[23];
    const float* td_W  = (const float*)d_in[24]; const float* td_b  = (const float*)d_in[25];

    float* out = (float*)d_out;
    float* out_L2   = out;
    float* out_mLp  = out + 4194304;
    float* out_mask = out + 8388608;
    float* out_txt  = out + 8454144;
    float* out_EO   = out + 139526144;

    char* ws = (char*)d_ws;
    size_t off = 0;
    auto alloc = [&](size_t bytes) -> void* {
        void* p = ws + off;
        off += (bytes + 255) & ~(size_t)255;
        return p;
    };

    bf16* wqa1 = (bf16*)alloc((size_t)DIN * D * 2);
    bf16* wqa2 = (bf16*)alloc((size_t)D * D * 2);
    bf16* wqb1 = (bf16*)alloc((size_t)DIN * D * 2);
    bf16* wqb2 = (bf16*)alloc((size_t)D * D * 2);
    bf16* wqc1 = (bf16*)alloc((size_t)DIN * D * 2);
    bf16* wqc2 = (bf16*)alloc((size_t)D * D * 2);
    bf16* wmd1 = (bf16*)alloc((size_t)D * D * 2);
    bf16* wek1 = (bf16*)alloc((size_t)E * D * D * 2);
    bf16* wek2 = (bf16*)alloc((size_t)E * D * D * 2);
    bf16* wtd  = (bf16*)alloc((size_t)D * V * 2);

    bf16* Lb   = (bf16*)alloc((size_t)Mtok * D * 2);
    bf16* mLb  = (bf16*)alloc((size_t)Mtok * D * 2);
    bf16* Pb   = (bf16*)alloc((size_t)Mtok * D * 2);
    bf16* Nb   = (bf16*)alloc((size_t)Mtok * D * 2);
    bf16* hbuf = (bf16*)alloc((size_t)Mtok * D * 2);
    bf16* L1b  = (bf16*)alloc((size_t)Mtok * D * 2);
    bf16* sLb  = (bf16*)alloc((size_t)Mtok * D * 2);
    bf16* tb   = (bf16*)alloc((size_t)Mtok * D * 2);
    bf16* qkb  = (bf16*)alloc((size_t)Mtok * D * 2);
    bf16* L2b  = (bf16*)alloc((size_t)Mtok * D * 2);
    float* paf = (float*)alloc((size_t)Mtok * D * 4);   // qa shared partial (fp32)

    const size_t hall_bytes = (size_t)E * Mtok * D * 2;
    bool batched = (off + hall_bytes + 256 <= ws_size);
    bf16* hall = batched ? (bf16*)alloc(hall_bytes) : nullptr;

    // fused activation conversions (1 launch)
    k_conv4<<<dim3(4 * 1048576 / 256), dim3(256), 0, stream>>>(
        L, mL, prompt, noise, Lb, mLb, Pb, Nb);

    // weight transposes (3 launches)
    k_transpose_3k<<<dim3(32, 96, 3), dim3(256), 0, stream>>>(
        qa_W1, qb_W1, qc_W1, wqa1, wqb1, wqc1);
    k_transpose_1k<<<dim3(32, 32, 36), dim3(256), 0, stream>>>(
        qa_W2, qb_W2, qc_W2, md_W1, ek_W1, ek_W2,
        wqa2, wqb2, wqc2, wmd1, wek1, wek2);
    k_transpose_f32_bf16<<<dim3(V / 32, D / 32), dim3(256), 0, stream>>>(td_W, wtd, D, V);

    const int nM128 = Mtok / 128;               // 32
    dim3 gph(nM128 * (D / 128), 1, 1);          // 256 WGs
    dim3 bph(512);

    // pa = prompt @ qaW1b + mL @ qaW1c   (K=2048, fp32 out)
    k_gemm128ph<0, 1, 0, 1, 0><<<gph, bph, 0, stream>>>(
        Pb, mLb, mLb, wqa1 + 1024, DIN, nullptr, nullptr,
        paf, D, nullptr, 0, 2048, nM128);

    // L1 = qa([L | prompt | mL]) : h = relu(L@W1a + pa + b1); L1 = h@W2 + b2
    k_gemm128ph<1, 0, 1, 0, 1><<<gph, bph, 0, stream>>>(
        Lb, Lb, Lb, wqa1, DIN, qa_b1, paf,
        nullptr, 0, hbuf, D, 1024, nM128);
    k_gemm128ph<0, 0, 0, 0, 1><<<gph, bph, 0, stream>>>(
        hbuf, hbuf, hbuf, wqa2, D, qa_b2, nullptr,
        nullptr, 0, L1b, D, 1024, nM128);

    // sL = qb([noise | prompt | L1])
    k_gemm128ph<1, 1, 0, 0, 1><<<gph, bph, 0, stream>>>(
        Nb, Pb, L1b, wqb1, DIN, qb_b1, nullptr,
        nullptr, 0, hbuf, D, 3072, nM128);
    k_gemm128ph<0, 0, 0, 0, 1><<<gph, bph, 0, stream>>>(
        hbuf, hbuf, hbuf, wqb2, D, qb_b2, nullptr,
        nullptr, 0, sLb, D, 1024, nM128);

    // mask = softmax(relu(sL @ md_W1 + b1) @ md_W2 + b2)
    k_gemm128ph<1, 0, 0, 0, 1><<<gph, bph, 0, stream>>>(
        sLb, sLb, sLb, wmd1, D, md_b1, nullptr,
        nullptr, 0, tb, D, 1024, nM128);
    k_mask_softmax<<<dim3(Mtok), dim3(64), 0, stream>>>(tb, md_W2, md_b2, out_mask);

    // experts via 256^2 phased kernel (z=16)
    if (batched) {
        dim3 ge(16 * 4, 1, 16), be(512);
        k_gemm256<2, 0, 1><<<ge, be, 0, stream>>>(
            L1b, D, 0, wek1, (long)D * D, ek_b1, D,
            nullptr, 0, 0, hall, D, (long)Mtok * D, D, 4);
        k_gemm256<0, 1, 0><<<ge, be, 0, stream>>>(
            hall, D, (long)Mtok * D, wek2, (long)D * D, ek_b2, D,
            out_EO, E * D, D, nullptr, 0, 0, D, 4);
    } else {
        dim3 b64(256);
        const int nM64 = Mtok / 64;
        dim3 g64(nM64 * (D / 128), 1, 1);
        for (int e = 0; e < 16; ++e) {
            k_gemm64<2, 0, 0><<<g64, b64, 0, stream>>>(
                L1b, L1b, L1b, wek1 + (size_t)e * D * D, D, 0, ek_b1 + e * D, 0, nullptr,
                nullptr, 0, hbuf, D, 1024, nM64);
            k_gemm64<0, 0, 0><<<g64, b64, 0, stream>>>(
                hbuf, hbuf, hbuf, wek2 + (size_t)e * D * D, D, 0, ek_b2 + e * D, 0, nullptr,
                out_EO + e * D, E * D, nullptr, 0, 1024, nM64);
        }
    }

    // qk = sum_e mask * EO
    k_qk<<<dim3(4096), dim3(256), 0, stream>>>(out_EO, out_mask, qkb);

    // L2 = qa([qk | prompt | mL]) : h = relu(qk@W1a + pa + b1); L2 = h@W2 + b2
    k_gemm128ph<1, 0, 1, 0, 1><<<gph, bph, 0, stream>>>(
        qkb, qkb, qkb, wqa1, DIN, qa_b1, paf,
        nullptr, 0, hbuf, D, 1024, nM128);
    k_gemm128ph<0, 0, 0, 1, 1><<<gph, bph, 0, stream>>>(
        hbuf, hbuf, hbuf, wqa2, D, qa_b2, nullptr,
        out_L2, D, L2b, D, 1024, nM128);

    // mL_pred = qc([mL | prompt | L2])
    k_gemm128ph<1, 1, 0, 0, 1><<<gph, bph, 0, stream>>>(
        mLb, Pb, L2b, wqc1, DIN, qc_b1, nullptr,
        nullptr, 0, hbuf, D, 3072, nM128);
    k_gemm128ph<0, 0, 0, 1, 0><<<gph, bph, 0, stream>>>(
        hbuf, hbuf, hbuf, wqc2, D, qc_b2, nullptr,
        out_mLp, D, nullptr, 0, 1024, nM128);

    // text_logits = L2 @ td_W + td_b  (256^2 phased)
    {
        dim3 gl(16 * 125, 1, 1), bl(512);
        k_gemm256<0, 1, 0><<<gl, bl, 0, stream>>>(
            L2b, D, 0, wtd, 0, td_b, 0,
            out_txt, V, 0, nullptr, 0, 0, D, 125);
    }
}

// Round 10
// 1083.862 us; speedup vs baseline: 1.5229x; 1.0227x over previous
//
#include <hip/hip_runtime.h>
#include <hip/hip_bf16.h>
#include <cstdint>
#include <cstddef>

using bf16 = __hip_bfloat16;

typedef __attribute__((ext_vector_type(4))) float f32x4;
typedef __attribute__((ext_vector_type(8))) short s16x8;

__device__ __forceinline__ bf16 to_bf16(float v) { return __float2bfloat16(v); }

struct alignas(8) bf16x4_pack { bf16 x, y, z, w; };

// bijective XCD-chunking swizzle (m204)
__device__ __forceinline__ int xcd_swz(int orig, int nwg) {
    int xcd = orig & 7, base = orig >> 3;
    int q = nwg >> 3, r = nwg & 7;
    return (xcd < r ? xcd * (q + 1) : r * (q + 1) + (xcd - r) * q) + base;
}

#define BAR()        asm volatile("s_barrier" ::: "memory")
#define WAITV4_BAR() asm volatile("s_waitcnt vmcnt(4)\ns_barrier" ::: "memory")
#define WAITV0_BAR() asm volatile("s_waitcnt vmcnt(0)\ns_barrier" ::: "memory")

// ---------------- fused fp32 -> bf16 conversion of the 4 activation inputs ----------------
__global__ void k_conv4(const float* __restrict__ a, const float* __restrict__ b,
                        const float* __restrict__ c, const float* __restrict__ d,
                        bf16* __restrict__ oa, bf16* __restrict__ ob,
                        bf16* __restrict__ oc, bf16* __restrict__ od)
{
    int i = blockIdx.x * blockDim.x + threadIdx.x;      // 4 * 1048576 units of 4 floats
    int sel = i >> 20, li = i & 1048575;
    const float* src = sel == 0 ? a : (sel == 1 ? b : (sel == 2 ? c : d));
    bf16* dst = sel == 0 ? oa : (sel == 1 ? ob : (sel == 2 ? oc : od));
    float4 v = ((const float4*)src)[li];
    bf16x4_pack o{to_bf16(v.x), to_bf16(v.y), to_bf16(v.z), to_bf16(v.w)};
    ((bf16x4_pack*)dst)[li] = o;
}

// ---------------- fp32 [K][N] -> bf16 [N][K] tiled transpose (single job) ----------------
__global__ __launch_bounds__(256) void k_transpose_f32_bf16(
    const float* __restrict__ in, bf16* __restrict__ out, int K, int N)
{
    __shared__ float t[32][33];
    int n0 = blockIdx.x * 32, k0 = blockIdx.y * 32;
    int tx = threadIdx.x & 31, ty = threadIdx.x >> 5;
#pragma unroll
    for (int r = 0; r < 32; r += 8)
        t[ty + r][tx] = in[(long)(k0 + ty + r) * N + (n0 + tx)];
    __syncthreads();
#pragma unroll
    for (int r = 0; r < 32; r += 8)
        out[(long)(n0 + ty + r) * K + (k0 + tx)] = to_bf16(t[tx][ty + r]);
}

// ---------------- multi-job transposes: 36 x (1024x1024) jobs, z-indexed ----------------
__global__ __launch_bounds__(256) void k_transpose_1k(
    const float* __restrict__ s0, const float* __restrict__ s1,
    const float* __restrict__ s2, const float* __restrict__ s3,
    const float* __restrict__ ek1, const float* __restrict__ ek2,
    bf16* __restrict__ d0, bf16* __restrict__ d1,
    bf16* __restrict__ d2, bf16* __restrict__ d3,
    bf16* __restrict__ dk1, bf16* __restrict__ dk2)
{
    __shared__ float t[32][33];
    const int z = blockIdx.z;
    const float* in; bf16* out;
    if (z < 4) {
        in  = z == 0 ? s0 : (z == 1 ? s1 : (z == 2 ? s2 : s3));
        out = z == 0 ? d0 : (z == 1 ? d1 : (z == 2 ? d2 : d3));
    } else if (z < 20) {
        in = ek1 + (long)(z - 4) * 1048576;  out = dk1 + (long)(z - 4) * 1048576;
    } else {
        in = ek2 + (long)(z - 20) * 1048576; out = dk2 + (long)(z - 20) * 1048576;
    }
    int n0 = blockIdx.x * 32, k0 = blockIdx.y * 32;
    int tx = threadIdx.x & 31, ty = threadIdx.x >> 5;
#pragma unroll
    for (int r = 0; r < 32; r += 8)
        t[ty + r][tx] = in[(long)(k0 + ty + r) * 1024 + (n0 + tx)];
    __syncthreads();
#pragma unroll
    for (int r = 0; r < 32; r += 8)
        out[(long)(n0 + ty + r) * 1024 + (k0 + tx)] = to_bf16(t[tx][ty + r]);
}

// ---------------- multi-job transposes: 3 x (3072x1024) jobs ----------------
__global__ __launch_bounds__(256) void k_transpose_3k(
    const float* __restrict__ s0, const float* __restrict__ s1, const float* __restrict__ s2,
    bf16* __restrict__ d0, bf16* __restrict__ d1, bf16* __restrict__ d2)
{
    __shared__ float t[32][33];
    const int z = blockIdx.z;
    const float* in = z == 0 ? s0 : (z == 1 ? s1 : s2);
    bf16* out = z == 0 ? d0 : (z == 1 ? d1 : d2);
    int n0 = blockIdx.x * 32, k0 = blockIdx.y * 32;
    int tx = threadIdx.x & 31, ty = threadIdx.x >> 5;
#pragma unroll
    for (int r = 0; r < 32; r += 8)
        t[ty + r][tx] = in[(long)(k0 + ty + r) * 1024 + (n0 + tx)];
    __syncthreads();
#pragma unroll
    for (int r = 0; r < 32; r += 8)
        out[(long)(n0 + ty + r) * 3072 + (k0 + tx)] = to_bf16(t[tx][ty + r]);
}

// ---------------- async global->LDS 16B helper ----------------
__device__ __forceinline__ void gload_lds16(const void* g, void* l) {
    __builtin_amdgcn_global_load_lds(
        (const __attribute__((address_space(1))) void*)g,
        (__attribute__((address_space(3))) void*)l,
        16, 0, 0);
}

// ================= 256x256 BK=64 8-wave phased GEMM (proven cadence) =================
// Round 10: bank-conflict-free swizzle — chunk' = g ^ ((row>>1)&3) (was g ^ (row&3),
// which left a 4-way conflict within each 16-lane ds_read_b128 group).
template<int ACT, int OUTF, int OUTB>   // ACT: 0 none, 1 relu, 2 silu
__global__ __launch_bounds__(512, 2) void k_gemm256(
    const bf16* __restrict__ A, int lda, long az,
    const bf16* __restrict__ W, long wz,
    const float* __restrict__ bias, long bz,
    float* __restrict__ Cf, int ldcf, long cfz,
    bf16* __restrict__ Cb, int ldcb, long cbz,
    int K, int nN)
{
    __shared__ char lds[131072];
    const int tid = threadIdx.x;
    const int wid = tid >> 6, lane = tid & 63;
    const int z = blockIdx.z;
    const int fid = xcd_swz(blockIdx.x, gridDim.x);
    const int m0 = (fid / nN) * 256;
    const int n0 = (fid % nN) * 256;
    const int wr = wid >> 2, wc = wid & 3;

    const int srow = tid >> 2;
    const int sk   = ((tid & 3) ^ ((srow >> 1) & 3)) * 8;   // conflict-free swizzle
    const bf16* Ag = A + (long)z * az + (long)(m0 + srow) * lda + sk;
    const bf16* Wg = W + (long)z * wz + (long)(n0 + srow) * K + sk;

    const int fr = lane & 15;
    const int xorv = (((lane >> 4) ^ ((lane >> 1) & 3)) << 4);   // matches staging involution
    const int aRd = wr * 16384 + fr * 64 + xorv;
    const int bRd = 65536 + (wc >> 1) * 16384 + ((wc & 1) << 12) + fr * 64 + xorv;

    f32x4 acc[8][4] = {};
    const int NT = K >> 6;

    auto issueA = [&](int db, int kh, int kb) {
        char* l = lds + db * 32768 + kh * 8192 + wid * 1024;
        gload_lds16(Ag + kb + kh * 32, l);
        gload_lds16(Ag + kb + kh * 32 + (long)128 * lda, l + 16384);
    };
    auto issueB = [&](int db, int kh, int kb) {
        char* l = lds + 65536 + db * 32768 + kh * 8192 + wid * 1024;
        gload_lds16(Wg + kb + kh * 32, l);
        gload_lds16(Wg + kb + kh * 32 + (long)128 * K, l + 16384);
    };

    issueA(0, 0, 0); issueB(0, 0, 0);
    issueA(0, 1, 0); issueB(0, 1, 0);
    WAITV4_BAR();

    for (int t = 0; t < NT; ++t) {
        const int db = t & 1, nb = db ^ 1;
        const int kn = (t + 1) << 6;
        const bool pf = (t + 1 < NT);
        const int abase = aRd + db * 32768;
        const int bbase = bRd + db * 32768;
        s16x8 a[4], b[4];

#pragma unroll
        for (int i = 0; i < 4; ++i) b[i] = *(const s16x8*)(lds + bbase + i * 1024);
#pragma unroll
        for (int i = 0; i < 4; ++i) a[i] = *(const s16x8*)(lds + abase + i * 1024);
        if (pf) issueA(nb, 0, kn);
        BAR();
        __builtin_amdgcn_s_setprio(1);
#pragma unroll
        for (int mi = 0; mi < 4; ++mi)
#pragma unroll
            for (int ni = 0; ni < 4; ++ni)
                acc[mi][ni] = __builtin_amdgcn_mfma_f32_16x16x32_bf16(a[mi], b[ni], acc[mi][ni], 0, 0, 0);
        __builtin_amdgcn_s_setprio(0);
        BAR();

#pragma unroll
        for (int i = 0; i < 4; ++i) a[i] = *(const s16x8*)(lds + abase + (4 + i) * 1024);
        if (pf) issueB(nb, 0, kn);
        BAR();
        __builtin_amdgcn_s_setprio(1);
#pragma unroll
        for (int mi = 0; mi < 4; ++mi)
#pragma unroll
            for (int ni = 0; ni < 4; ++ni)
                acc[4 + mi][ni] = __builtin_amdgcn_mfma_f32_16x16x32_bf16(a[mi], b[ni], acc[4 + mi][ni], 0, 0, 0);
        __builtin_amdgcn_s_setprio(0);
        if (pf) { WAITV4_BAR(); }
        else    { WAITV0_BAR(); }

#pragma unroll
        for (int i = 0; i < 4; ++i) b[i] = *(const s16x8*)(lds + bbase + 8192 + i * 1024);
#pragma unroll
        for (int i = 0; i < 4; ++i) a[i] = *(const s16x8*)(lds + abase + 8192 + i * 1024);
        if (pf) issueA(nb, 1, kn);
        BAR();
        __builtin_amdgcn_s_setprio(1);
#pragma unroll
        for (int mi = 0; mi < 4; ++mi)
#pragma unroll
            for (int ni = 0; ni < 4; ++ni)
                acc[mi][ni] = __builtin_amdgcn_mfma_f32_16x16x32_bf16(a[mi], b[ni], acc[mi][ni], 0, 0, 0);
        __builtin_amdgcn_s_setprio(0);
        BAR();

#pragma unroll
        for (int i = 0; i < 4; ++i) a[i] = *(const s16x8*)(lds + abase + 8192 + (4 + i) * 1024);
        if (pf) issueB(nb, 1, kn);
        BAR();
        __builtin_amdgcn_s_setprio(1);
#pragma unroll
        for (int mi = 0; mi < 4; ++mi)
#pragma unroll
            for (int ni = 0; ni < 4; ++ni)
                acc[4 + mi][ni] = __builtin_amdgcn_mfma_f32_16x16x32_bf16(a[mi], b[ni], acc[4 + mi][ni], 0, 0, 0);
        __builtin_amdgcn_s_setprio(0);
        if (pf) { WAITV4_BAR(); }
    }

    // ---- vectorized epilogue: per-wave LDS transpose staging ----
    __syncthreads();   // main-loop LDS traffic fully drained before reuse
    float* scb = (float*)(lds + wid * 16384);   // wave-private 16KB; 2 x 4KB chunks used
    const int rb = (lane >> 4) * 4;
    const int rrow = lane >> 4;          // read row-in-group 0..3
    const int rcol = (lane & 15) * 4;    // read col 0..60
    const int colv = n0 + wc * 64 + rcol;
    float4 bv4 = *(const float4*)(bias + (long)z * bz + colv);
#pragma unroll
    for (int mi = 0; mi < 8; ++mi) {
        float* sc = scb + (mi & 1) * 1024;    // alternate 4KB chunks
#pragma unroll
        for (int ni = 0; ni < 4; ++ni)
#pragma unroll
            for (int r = 0; r < 4; ++r)
                sc[(rb + r) * 64 + ni * 16 + fr] = acc[mi][ni][r];
        asm volatile("s_waitcnt lgkmcnt(0)" ::: "memory");   // wave-local writes visible
#pragma unroll
        for (int it = 0; it < 4; ++it) {
            const int row = m0 + wr * 128 + mi * 16 + it * 4 + rrow;
            f32x4 v4 = *(const f32x4*)(sc + (it * 4 + rrow) * 64 + rcol);
            float vv[4];
#pragma unroll
            for (int j = 0; j < 4; ++j) {
                float v = v4[j] + (&bv4.x)[j];
                if (ACT == 1) v = fmaxf(v, 0.f);
                if (ACT == 2) v = v / (1.f + __expf(-v));
                vv[j] = v;
            }
            if (OUTF)
                *(float4*)(Cf + (long)z * cfz + (long)row * ldcf + colv) =
                    make_float4(vv[0], vv[1], vv[2], vv[3]);
            if (OUTB) {
                bf16x4_pack o{to_bf16(vv[0]), to_bf16(vv[1]), to_bf16(vv[2]), to_bf16(vv[3])};
                *(bf16x4_pack*)(Cb + (long)z * cbz + (long)row * ldcb + colv) = o;
            }
        }
    }
}

// ================= 128x128 BK=128 8-wave phased GEMM, 2 merged phases/K-tile =================
template<int ACT, int SEG, int ADD, int OUTF, int OUTB>
__global__ __launch_bounds__(512, 2) void k_gemm128ph(
    const bf16* __restrict__ A0, const bf16* __restrict__ A1, const bf16* __restrict__ A2,
    const bf16* __restrict__ W, int ldb,
    const float* __restrict__ bias,
    const float* __restrict__ Add,
    float* __restrict__ Cf, int ldcf,
    bf16* __restrict__ Cb, int ldcb,
    int K, int nM)
{
    __shared__ char lds[131072];
    const int tid = threadIdx.x;
    const int wid = tid >> 6, lane = tid & 63;
    const int fid = xcd_swz(blockIdx.x, gridDim.x);
    const int m0 = (fid % nM) * 128;
    const int n0 = (fid / nM) * 128;
    const int wr = wid >> 1, wc = wid & 1;

    const int trow = tid >> 3;
    const int swzc = ((tid & 7) ^ (trow & 7)) * 8;
    const long aoff0 = (long)(m0 + trow) * 1024 + swzc;
    const long aoff1 = aoff0 + (long)64 * 1024;
    const long boff0 = (long)(n0 + trow) * ldb + swzc;
    const long boff1 = boff0 + (long)64 * ldb;

    const int fr = lane & 15, g = lane >> 4;
    const int ch0 = ((g ^ (fr & 7)) << 4);
    const int ch1 = (((4 + g) ^ (fr & 7)) << 4);
    const int arow = (wr * 32 + fr) * 128;
    const int brow = 65536 + (wc * 64 + fr) * 128;

    f32x4 acc[2][4] = {};
    const int NT = K >> 7;

    auto issueA = [&](int db, int kh, const bf16* base, int ko) {
        char* l = lds + db * 32768 + kh * 16384 + wid * 1024;
        gload_lds16(base + aoff0 + ko + kh * 64, l);
        gload_lds16(base + aoff1 + ko + kh * 64, l + 8192);
    };
    auto issueB = [&](int db, int kh, int kfull) {
        char* l = lds + 65536 + db * 32768 + kh * 16384 + wid * 1024;
        gload_lds16(W + boff0 + kfull + kh * 64, l);
        gload_lds16(W + boff1 + kfull + kh * 64, l + 8192);
    };
    auto aseg = [&](int k0, const bf16*& base, int& ko) {
        if (SEG) { int s = k0 >> 10; base = (s == 0 ? A0 : (s == 1 ? A1 : A2)); ko = k0 & 1023; }
        else     { base = A0; ko = k0; }
    };

    { const bf16* b0; int k0o; aseg(0, b0, k0o);
      issueA(0, 0, b0, k0o); issueB(0, 0, 0);
      issueA(0, 1, b0, k0o); issueB(0, 1, 0); }
    WAITV4_BAR();

    for (int t = 0; t < NT; ++t) {
        const int db = t & 1, nb = db ^ 1;
        const int kn = (t + 1) << 7;
        const bool pf = (t + 1 < NT);
        const bf16* nab = A0; int nko = 0;
        if (pf) aseg(kn, nab, nko);
        const int ab = db * 32768, bb = db * 32768;
        s16x8 a0[2], a1[2], b0[4], b1[4];

#pragma unroll
        for (int i = 0; i < 4; ++i) b0[i] = *(const s16x8*)(lds + bb + brow + i * 2048 + ch0);
#pragma unroll
        for (int i = 0; i < 4; ++i) b1[i] = *(const s16x8*)(lds + bb + brow + i * 2048 + ch1);
#pragma unroll
        for (int i = 0; i < 2; ++i) a0[i] = *(const s16x8*)(lds + ab + arow + i * 2048 + ch0);
#pragma unroll
        for (int i = 0; i < 2; ++i) a1[i] = *(const s16x8*)(lds + ab + arow + i * 2048 + ch1);
        if (pf) { issueA(nb, 0, nab, nko); issueB(nb, 0, kn); }
        BAR();
        __builtin_amdgcn_s_setprio(1);
#pragma unroll
        for (int mi = 0; mi < 2; ++mi)
#pragma unroll
            for (int ni = 0; ni < 4; ++ni)
                acc[mi][ni] = __builtin_amdgcn_mfma_f32_16x16x32_bf16(a0[mi], b0[ni], acc[mi][ni], 0, 0, 0);
#pragma unroll
        for (int mi = 0; mi < 2; ++mi)
#pragma unroll
            for (int ni = 0; ni < 4; ++ni)
                acc[mi][ni] = __builtin_amdgcn_mfma_f32_16x16x32_bf16(a1[mi], b1[ni], acc[mi][ni], 0, 0, 0);
        __builtin_amdgcn_s_setprio(0);
        if (pf) { WAITV4_BAR(); }
        else    { WAITV0_BAR(); }

#pragma unroll
        for (int i = 0; i < 4; ++i) b0[i] = *(const s16x8*)(lds + bb + 16384 + brow + i * 2048 + ch0);
#pragma unroll
        for (int i = 0; i < 4; ++i) b1[i] = *(const s16x8*)(lds + bb + 16384 + brow + i * 2048 + ch1);
#pragma unroll
        for (int i = 0; i < 2; ++i) a0[i] = *(const s16x8*)(lds + ab + 16384 + arow + i * 2048 + ch0);
#pragma unroll
        for (int i = 0; i < 2; ++i) a1[i] = *(const s16x8*)(lds + ab + 16384 + arow + i * 2048 + ch1);
        if (pf) { issueA(nb, 1, nab, nko); issueB(nb, 1, kn); }
        BAR();
        __builtin_amdgcn_s_setprio(1);
#pragma unroll
        for (int mi = 0; mi < 2; ++mi)
#pragma unroll
            for (int ni = 0; ni < 4; ++ni)
                acc[mi][ni] = __builtin_amdgcn_mfma_f32_16x16x32_bf16(a0[mi], b0[ni], acc[mi][ni], 0, 0, 0);
#pragma unroll
        for (int mi = 0; mi < 2; ++mi)
#pragma unroll
            for (int ni = 0; ni < 4; ++ni)
                acc[mi][ni] = __builtin_amdgcn_mfma_f32_16x16x32_bf16(a1[mi], b1[ni], acc[mi][ni], 0, 0, 0);
        __builtin_amdgcn_s_setprio(0);
        if (pf) { WAITV4_BAR(); }
    }

    const int rb = g * 4;
#pragma unroll
    for (int ni = 0; ni < 4; ++ni) {
        const int col = n0 + wc * 64 + ni * 16 + fr;
        const float bv = bias ? bias[col] : 0.f;
#pragma unroll
        for (int mi = 0; mi < 2; ++mi) {
#pragma unroll
            for (int r = 0; r < 4; ++r) {
                const int row = m0 + wr * 32 + mi * 16 + rb + r;
                float v = acc[mi][ni][r] + bv;
                if (ADD) v += Add[(long)row * 1024 + col];
                if (ACT == 1) v = fmaxf(v, 0.f);
                if (ACT == 2) v = v / (1.f + __expf(-v));
                if (OUTF) Cf[(long)row * ldcf + col] = v;
                if (OUTB) Cb[(long)row * ldcb + col] = to_bf16(v);
            }
        }
    }
}

// ================= 64x128 m97-style GEMM (fallback path only) =================
template<int ACT, int SEG, int ADD>
__global__ __launch_bounds__(256, 4) void k_gemm64(
    const bf16* __restrict__ A0, const bf16* __restrict__ A1, const bf16* __restrict__ A2,
    const bf16* __restrict__ W, int ldb, long wz,
    const float* __restrict__ bias, long bz,
    const float* __restrict__ Add,
    float* __restrict__ Cf, int ldcf,
    bf16* __restrict__ Cb, int ldcb,
    int K, int nM)
{
    __shared__ bf16 As[64 * 32];
    __shared__ bf16 Bs[128 * 32];
    const int tid  = threadIdx.x;
    const int wid  = tid >> 6;
    const int lane = tid & 63;
    const int z = blockIdx.z;

    const int fid = xcd_swz(blockIdx.x, gridDim.x);
    const int m0 = (fid % nM) * 64;
    const int n0 = (fid / nM) * 128;

    const int srow = tid >> 2;
    const int scol = (tid & 3) * 8;
    const long arow = (long)(m0 + srow) * 1024 + scol;
    const bf16* a0 = A0 + arow;
    const bf16* a1 = SEG ? (A1 + arow) : nullptr;
    const bf16* a2 = SEG ? (A2 + arow) : nullptr;
    const bf16* bg = W + (long)z * wz + (long)(n0 + srow) * ldb + scol;

    char* asb = (char*)As;
    char* bsb = (char*)Bs;

    f32x4 acc[2][4] = {};

    const int wm = (wid >> 1) * 32;
    const int wn = (wid & 1) * 64;
    const int fr = lane & 15;
    const int kq = (lane >> 4) * 8;

    for (int k0 = 0; k0 < K; k0 += 32) {
        const bf16* ap;
        if (SEG) {
            const int seg = k0 >> 10, ko = k0 & 1023;
            ap = (seg == 0 ? a0 : (seg == 1 ? a1 : a2)) + ko;
        } else {
            ap = a0 + k0;
        }
        const bf16* bp = bg + k0;

        __syncthreads();
        gload_lds16(ap,                   asb + wid * 1024);
        gload_lds16(bp,                   bsb + wid * 1024);
        gload_lds16(bp + (long)64 * ldb,  bsb + 4096 + wid * 1024);
        __syncthreads();

        s16x8 af[2], bfv[4];
#pragma unroll
        for (int i = 0; i < 2; ++i)
            af[i] = *(const s16x8*)(As + (wm + i * 16 + fr) * 32 + kq);
#pragma unroll
        for (int i = 0; i < 4; ++i)
            bfv[i] = *(const s16x8*)(Bs + (wn + i * 16 + fr) * 32 + kq);
#pragma unroll
        for (int mi = 0; mi < 2; ++mi)
#pragma unroll
            for (int ni = 0; ni < 4; ++ni)
                acc[mi][ni] = __builtin_amdgcn_mfma_f32_16x16x32_bf16(
                    af[mi], bfv[ni], acc[mi][ni], 0, 0, 0);
    }

    const int rb = (lane >> 4) * 4;
#pragma unroll
    for (int ni = 0; ni < 4; ++ni) {
        const int col = n0 + wn + ni * 16 + fr;
        const float bv = bias ? bias[(long)z * bz + col] : 0.f;
#pragma unroll
        for (int mi = 0; mi < 2; ++mi) {
#pragma unroll
            for (int r = 0; r < 4; ++r) {
                const int row = m0 + wm + mi * 16 + rb + r;
                float v = acc[mi][ni][r] + bv;
                if (ADD) v += Add[(long)row * 1024 + col];
                if (ACT == 1) v = fmaxf(v, 0.f);
                if (ACT == 2) v = v / (1.f + __expf(-v));
                if (Cf) Cf[(long)row * ldcf + col] = v;
                if (Cb) Cb[(long)row * ldcb + col] = to_bf16(v);
            }
        }
    }
}

// ---------------- fused mask head ----------------
__global__ __launch_bounds__(64) void k_mask_softmax(
    const bf16* __restrict__ t, const float* __restrict__ W2,
    const float* __restrict__ b2, float* __restrict__ mask_out)
{
    const int tok = blockIdx.x;
    const int lane = threadIdx.x;
    float part[16];
#pragma unroll
    for (int e = 0; e < 16; ++e) part[e] = 0.f;
    const bf16* tr = t + (long)tok * 1024 + lane * 16;
#pragma unroll
    for (int kk = 0; kk < 16; ++kk) {
        float x = __bfloat162float(tr[kk]);
        const float* wr = W2 + (long)(lane * 16 + kk) * 16;
#pragma unroll
        for (int e = 0; e < 16; ++e) part[e] += x * wr[e];
    }
#pragma unroll
    for (int e = 0; e < 16; ++e) {
#pragma unroll
        for (int off = 32; off >= 1; off >>= 1)
            part[e] += __shfl_down(part[e], off);
    }
    if (lane == 0) {
        float vals[16], mx = -1e30f;
#pragma unroll
        for (int e = 0; e < 16; ++e) { vals[e] = part[e] + b2[e]; mx = fmaxf(mx, vals[e]); }
        float s = 0.f;
#pragma unroll
        for (int e = 0; e < 16; ++e) { vals[e] = __expf(vals[e] - mx); s += vals[e]; }
        float inv = 1.f / s;
#pragma unroll
        for (int e = 0; e < 16; ++e) mask_out[tok * 16 + e] = vals[e] * inv;
    }
}

// ---------------- qk = sum_e mask[tok][e] * EO[tok][e][:] -> bf16 ----------------
__global__ void k_qk(const float* __restrict__ EO, const float* __restrict__ mask,
                     bf16* __restrict__ qkb)
{
    int i = blockIdx.x * blockDim.x + threadIdx.x;
    int tok = i >> 8;
    int d4  = (i & 255) << 2;
    const float* eo = EO + (long)tok * 16384 + d4;
    const float* mk = mask + tok * 16;
    float4 s = make_float4(0.f, 0.f, 0.f, 0.f);
#pragma unroll
    for (int e = 0; e < 16; ++e) {
        float m = mk[e];
        float4 v = *(const float4*)(eo + e * 1024);
        s.x += m * v.x; s.y += m * v.y; s.z += m * v.z; s.w += m * v.w;
    }
    bf16x4_pack o{to_bf16(s.x), to_bf16(s.y), to_bf16(s.z), to_bf16(s.w)};
    ((bf16x4_pack*)qkb)[i] = o;
}

extern "C" void kernel_launch(void* const* d_in, const int* in_sizes, int n_in,
                              void* d_out, int out_size, void* d_ws, size_t ws_size,
                              hipStream_t stream)
{
    const int Mtok = 4096, D = 1024, E = 16, V = 32000, DIN = 3072;

    const float* L      = (const float*)d_in[0];
    const float* mL     = (const float*)d_in[1];
    const float* prompt = (const float*)d_in[2];
    const float* noise  = (const float*)d_in[3];
    const float* qa_W1 = (const float*)d_in[4];  const float* qa_b1 = (const float*)d_in[5];
    const float* qa_W2 = (const float*)d_in[6];  const float* qa_b2 = (const float*)d_in[7];
    const float* qb_W1 = (const float*)d_in[8];  const float* qb_b1 = (const float*)d_in[9];
    const float* qb_W2 = (const float*)d_in[10]; const float* qb_b2 = (const float*)d_in[11];
    const float* qc_W1 = (const float*)d_in[12]; const float* qc_b1 = (const float*)d_in[13];
    const float* qc_W2 = (const float*)d_in[14]; const float* qc_b2 = (const float*)d_in[15];
    const float* ek_W1 = (const float*)d_in[16]; const float* ek_b1 = (const float*)d_in[17];
    const float* ek_W2 = (const float*)d_in[18]; const float* ek_b2 = (const float*)d_in[19];
    const float* md_W1 = (const float*)d_in[20]; const float* md_b1 = (const float*)d_in[21];
    const float* md_W2 = (const float*)d_in[22]; const float* md_b2 = (const float*)d_in[23];
    const float* td_W  = (const float*)d_in[24]; const float* td_b  = (const float*)d_in[25];

    float* out = (float*)d_out;
    float* out_L2   = out;
    float* out_mLp  = out + 4194304;
    float* out_mask = out + 8388608;
    float* out_txt  = out + 8454144;
    float* out_EO   = out + 139526144;

    char* ws = (char*)d_ws;
    size_t off = 0;
    auto alloc = [&](size_t bytes) -> void* {
        void* p = ws + off;
        off += (bytes + 255) & ~(size_t)255;
        return p;
    };

    bf16* wqa1 = (bf16*)alloc((size_t)DIN * D * 2);
    bf16* wqa2 = (bf16*)alloc((size_t)D * D * 2);
    bf16* wqb1 = (bf16*)alloc((size_t)DIN * D * 2);
    bf16* wqb2 = (bf16*)alloc((size_t)D * D * 2);
    bf16* wqc1 = (bf16*)alloc((size_t)DIN * D * 2);
    bf16* wqc2 = (bf16*)alloc((size_t)D * D * 2);
    bf16* wmd1 = (bf16*)alloc((size_t)D * D * 2);
    bf16* wek1 = (bf16*)alloc((size_t)E * D * D * 2);
    bf16* wek2 = (bf16*)alloc((size_t)E * D * D * 2);
    bf16* wtd  = (bf16*)alloc((size_t)D * V * 2);

    bf16* Lb   = (bf16*)alloc((size_t)Mtok * D * 2);
    bf16* mLb  = (bf16*)alloc((size_t)Mtok * D * 2);
    bf16* Pb   = (bf16*)alloc((size_t)Mtok * D * 2);
    bf16* Nb   = (bf16*)alloc((size_t)Mtok * D * 2);
    bf16* hbuf = (bf16*)alloc((size_t)Mtok * D * 2);
    bf16* L1b  = (bf16*)alloc((size_t)Mtok * D * 2);
    bf16* sLb  = (bf16*)alloc((size_t)Mtok * D * 2);
    bf16* tb   = (bf16*)alloc((size_t)Mtok * D * 2);
    bf16* qkb  = (bf16*)alloc((size_t)Mtok * D * 2);
    bf16* L2b  = (bf16*)alloc((size_t)Mtok * D * 2);
    float* paf = (float*)alloc((size_t)Mtok * D * 4);   // qa shared partial (fp32)

    const size_t hall_bytes = (size_t)E * Mtok * D * 2;
    bool batched = (off + hall_bytes + 256 <= ws_size);
    bf16* hall = batched ? (bf16*)alloc(hall_bytes) : nullptr;

    // fused activation conversions (1 launch)
    k_conv4<<<dim3(4 * 1048576 / 256), dim3(256), 0, stream>>>(
        L, mL, prompt, noise, Lb, mLb, Pb, Nb);

    // weight transposes (3 launches)
    k_transpose_3k<<<dim3(32, 96, 3), dim3(256), 0, stream>>>(
        qa_W1, qb_W1, qc_W1, wqa1, wqb1, wqc1);
    k_transpose_1k<<<dim3(32, 32, 36), dim3(256), 0, stream>>>(
        qa_W2, qb_W2, qc_W2, md_W1, ek_W1, ek_W2,
        wqa2, wqb2, wqc2, wmd1, wek1, wek2);
    k_transpose_f32_bf16<<<dim3(V / 32, D / 32), dim3(256), 0, stream>>>(td_W, wtd, D, V);

    const int nM128 = Mtok / 128;               // 32
    dim3 gph(nM128 * (D / 128), 1, 1);          // 256 WGs
    dim3 bph(512);

    // pa = prompt @ qaW1b + mL @ qaW1c   (K=2048, fp32 out)
    k_gemm128ph<0, 1, 0, 1, 0><<<gph, bph, 0, stream>>>(
        Pb, mLb, mLb, wqa1 + 1024, DIN, nullptr, nullptr,
        paf, D, nullptr, 0, 2048, nM128);

    // L1 = qa([L | prompt | mL]) : h = relu(L@W1a + pa + b1); L1 = h@W2 + b2
    k_gemm128ph<1, 0, 1, 0, 1><<<gph, bph, 0, stream>>>(
        Lb, Lb, Lb, wqa1, DIN, qa_b1, paf,
        nullptr, 0, hbuf, D, 1024, nM128);
    k_gemm128ph<0, 0, 0, 0, 1><<<gph, bph, 0, stream>>>(
        hbuf, hbuf, hbuf, wqa2, D, qa_b2, nullptr,
        nullptr, 0, L1b, D, 1024, nM128);

    // sL = qb([noise | prompt | L1])
    k_gemm128ph<1, 1, 0, 0, 1><<<gph, bph, 0, stream>>>(
        Nb, Pb, L1b, wqb1, DIN, qb_b1, nullptr,
        nullptr, 0, hbuf, D, 3072, nM128);
    k_gemm128ph<0, 0, 0, 0, 1><<<gph, bph, 0, stream>>>(
        hbuf, hbuf, hbuf, wqb2, D, qb_b2, nullptr,
        nullptr, 0, sLb, D, 1024, nM128);

    // mask = softmax(relu(sL @ md_W1 + b1) @ md_W2 + b2)
    k_gemm128ph<1, 0, 0, 0, 1><<<gph, bph, 0, stream>>>(
        sLb, sLb, sLb, wmd1, D, md_b1, nullptr,
        nullptr, 0, tb, D, 1024, nM128);
    k_mask_softmax<<<dim3(Mtok), dim3(64), 0, stream>>>(tb, md_W2, md_b2, out_mask);

    // experts via 256^2 phased kernel (z=16)
    if (batched) {
        dim3 ge(16 * 4, 1, 16), be(512);
        k_gemm256<2, 0, 1><<<ge, be, 0, stream>>>(
            L1b, D, 0, wek1, (long)D * D, ek_b1, D,
            nullptr, 0, 0, hall, D, (long)Mtok * D, D, 4);
        k_gemm256<0, 1, 0><<<ge, be, 0, stream>>>(
            hall, D, (long)Mtok * D, wek2, (long)D * D, ek_b2, D,
            out_EO, E * D, D, nullptr, 0, 0, D, 4);
    } else {
        dim3 b64(256);
        const int nM64 = Mtok / 64;
        dim3 g64(nM64 * (D / 128), 1, 1);
        for (int e = 0; e < 16; ++e) {
            k_gemm64<2, 0, 0><<<g64, b64, 0, stream>>>(
                L1b, L1b, L1b, wek1 + (size_t)e * D * D, D, 0, ek_b1 + e * D, 0, nullptr,
                nullptr, 0, hbuf, D, 1024, nM64);
            k_gemm64<0, 0, 0><<<g64, b64, 0, stream>>>(
                hbuf, hbuf, hbuf, wek2 + (size_t)e * D * D, D, 0, ek_b2 + e * D, 0, nullptr,
                out_EO + e * D, E * D, nullptr, 0, 1024, nM64);
        }
    }

    // qk = sum_e mask * EO
    k_qk<<<dim3(4096), dim3(256), 0, stream>>>(out_EO, out_mask, qkb);

    // L2 = qa([qk | prompt | mL]) : h = relu(qk@W1a + pa + b1); L2 = h@W2 + b2
    k_gemm128ph<1, 0, 1, 0, 1><<<gph, bph, 0, stream>>>(
        qkb, qkb, qkb, wqa1, DIN, qa_b1, paf,
        nullptr, 0, hbuf, D, 1024, nM128);
    k_gemm128ph<0, 0, 0, 1, 1><<<gph, bph, 0, stream>>>(
        hbuf, hbuf, hbuf, wqa2, D, qa_b2, nullptr,
        out_L2, D, L2b, D, 1024, nM128);

    // mL_pred = qc([mL | prompt | L2])
    k_gemm128ph<1, 1, 0, 0, 1><<<gph, bph, 0, stream>>>(
        mLb, Pb, L2b, wqc1, DIN, qc_b1, nullptr,
        nullptr, 0, hbuf, D, 3072, nM128);
    k_gemm128ph<0, 0, 0, 1, 0><<<gph, bph, 0, stream>>>(
        hbuf, hbuf, hbuf, wqc2, D, qc_b2, nullptr,
        out_mLp, D, nullptr, 0, 1024, nM128);

    // text_logits = L2 @ td_W + td_b  (256^2 phased)
    {
        dim3 gl(16 * 125, 1, 1), bl(512);
        k_gemm256<0, 1, 0><<<gl, bl, 0, stream>>>(
            L2b, D, 0, wtd, 0, td_b, 0,
            out_txt, V, 0, nullptr, 0, 0, D, 125);
    }
}